// Round 1
// baseline (7365.027 us; speedup 1.0000x reference)
//
#include <hip/hip_runtime.h>
#include <math.h>

#define BSZ 16
#define LQ 1024
#define DM 256
#define DI 512
#define NT (BSZ*LQ)   // 16384 tokens

// ---------------- stem: conv1d(k=3,pad=1) + bias + relu, output (B,L,DM) ----------------
__global__ void stem_kernel(const float* __restrict__ x, const float* __restrict__ w,
                            const float* __restrict__ bias, float* __restrict__ h) {
  int idx = blockIdx.x * 256 + threadIdx.x;   // over NT*DM = 4M
  int d = idx & 255;
  int l = (idx >> 8) & 1023;
  int b = idx >> 18;
  float acc = bias[d];
#pragma unroll
  for (int c = 0; c < 3; c++) {
    const float* xr = x + (size_t)(b * 3 + c) * LQ;
    const float* wr = w + (size_t)(d * 3 + c) * 3;
#pragma unroll
    for (int k = 0; k < 3; k++) {
      int t = l + k - 1;
      if (t >= 0 && t < LQ) acc += xr[t] * wr[k];
    }
  }
  h[idx] = fmaxf(acc, 0.f);
}

// ---------------- layernorm over DM=256, one block per token ----------------
__global__ void ln_kernel(const float* __restrict__ x, const float* __restrict__ g,
                          const float* __restrict__ bv, float* __restrict__ o) {
  int token = blockIdx.x;
  int d = threadIdx.x;
  float v = x[(size_t)token * DM + d];
  float s = v, q = v * v;
#pragma unroll
  for (int off = 32; off > 0; off >>= 1) {
    s += __shfl_down(s, off, 64);
    q += __shfl_down(q, off, 64);
  }
  __shared__ float ss[4], qq[4];
  int lane = d & 63, wid = d >> 6;
  if (lane == 0) { ss[wid] = s; qq[wid] = q; }
  __syncthreads();
  s = ss[0] + ss[1] + ss[2] + ss[3];
  q = qq[0] + qq[1] + qq[2] + qq[3];
  float mu = s * (1.f / DM);
  float var = q * (1.f / DM) - mu * mu;
  float rs = rsqrtf(var + 1e-5f);
  o[(size_t)token * DM + d] = (v - mu) * rs * g[d] + bv[d];
}

// ---------------- generic fp32 GEMM: C[M,N] (+)= A[M,K(lda)] * W[N,K]^T ----------------
// 64x64 tile, 256 threads, 4x4 per thread. M multiple of 64; N,K arbitrary-ish (K%16==0).
__global__ void gemm_tn(const float* __restrict__ A, int lda,
                        const float* __restrict__ W,
                        float* __restrict__ C, int ldc,
                        int N, int K, int accum) {
  __shared__ float As[16][65];
  __shared__ float Ws[16][65];
  int tid = threadIdx.x;
  int bm = blockIdx.y * 64, bn = blockIdx.x * 64;
  int lm = tid >> 2;          // 0..63
  int lk = (tid & 3) << 2;    // 0,4,8,12
  int tx = tid & 15, ty = tid >> 4;
  float acc[4][4];
#pragma unroll
  for (int i = 0; i < 4; i++)
#pragma unroll
    for (int j = 0; j < 4; j++) acc[i][j] = 0.f;

  for (int k0 = 0; k0 < K; k0 += 16) {
    float4 av = *(const float4*)(A + (size_t)(bm + lm) * lda + k0 + lk);
    float4 wv = make_float4(0.f, 0.f, 0.f, 0.f);
    int wn = bn + lm;
    if (wn < N) wv = *(const float4*)(W + (size_t)wn * K + k0 + lk);
    As[lk + 0][lm] = av.x; As[lk + 1][lm] = av.y; As[lk + 2][lm] = av.z; As[lk + 3][lm] = av.w;
    Ws[lk + 0][lm] = wv.x; Ws[lk + 1][lm] = wv.y; Ws[lk + 2][lm] = wv.z; Ws[lk + 3][lm] = wv.w;
    __syncthreads();
#pragma unroll
    for (int k = 0; k < 16; k++) {
      float a[4], bb[4];
#pragma unroll
      for (int i = 0; i < 4; i++) a[i] = As[k][ty * 4 + i];
#pragma unroll
      for (int j = 0; j < 4; j++) bb[j] = Ws[k][tx * 4 + j];
#pragma unroll
      for (int i = 0; i < 4; i++)
#pragma unroll
        for (int j = 0; j < 4; j++) acc[i][j] += a[i] * bb[j];
    }
    __syncthreads();
  }
#pragma unroll
  for (int i = 0; i < 4; i++) {
    int m = bm + ty * 4 + i;
#pragma unroll
    for (int j = 0; j < 4; j++) {
      int n = bn + tx * 4 + j;
      if (n < N) {
        float* p = C + (size_t)m * ldc + n;
        *p = (accum ? *p : 0.f) + acc[i][j];
      }
    }
  }
}

// ---------------- causal depthwise conv (k=4, left pad 3) + bias + silu ----------------
// reads x-half of xz (B,L,1024 layout, cols [0,512)), writes xin (B,L,512)
__global__ void conv_silu_kernel(const float* __restrict__ xz, const float* __restrict__ cw,
                                 const float* __restrict__ cb, float* __restrict__ xin) {
  int idx = blockIdx.x * 256 + threadIdx.x;   // over NT*DI = 8M
  int d = idx & 511;
  int l = (idx >> 9) & 1023;
  int b = idx >> 19;
  float acc = cb[d];
  const float* base = xz + (size_t)b * LQ * 1024 + d;
#pragma unroll
  for (int k = 0; k < 4; k++) {
    int t = l + k - 3;
    if (t >= 0) acc += base[(size_t)t * 1024] * cw[d * 4 + k];
  }
  xin[idx] = acc / (1.f + expf(-acc));
}

// ---------------- fused delta-proj + selective scan + Dp skip + silu(z) gate ----------------
// grid: B * (DI/64) = 128 blocks of 64 threads; one thread = one (b,d) chain.
// y written into x-half of xz (stride 1024).
__global__ void scan_kernel(const float* __restrict__ xin, const float* __restrict__ proj,
                            const float* __restrict__ xz,
                            const float* __restrict__ dt_w, const float* __restrict__ dt_b,
                            const float* __restrict__ A_log, const float* __restrict__ Dp,
                            float* __restrict__ yout) {
  int b = blockIdx.x >> 3;
  int d = ((blockIdx.x & 7) << 6) + threadIdx.x;
  float Av[16], wv[16], h[16];
#pragma unroll
  for (int s = 0; s < 16; s++) {
    Av[s] = -expf(A_log[d * 16 + s]);
    wv[s] = dt_w[d * 16 + s];
    h[s] = 0.f;
  }
  float db = dt_b[d], Dd = Dp[d];
  __shared__ float sP[48];
  const float* projb = proj + (size_t)b * LQ * 48;
  const float* xinb = xin + (size_t)b * LQ * 512 + d;
  const float* zb = xz + (size_t)b * LQ * 1024 + 512 + d;
  float* yb = yout + (size_t)b * LQ * 1024 + d;
  for (int t = 0; t < LQ; t++) {
    if (threadIdx.x < 48) sP[threadIdx.x] = projb[t * 48 + threadIdx.x];
    __syncthreads();
    float dt = db;
#pragma unroll
    for (int r = 0; r < 16; r++) dt += sP[r] * wv[r];
    float delta = (dt > 20.f) ? dt : log1pf(expf(dt));
    float u = xinb[(size_t)t * 512];
    float z = zb[(size_t)t * 1024];
    float du = delta * u;
    float yv = 0.f;
#pragma unroll
    for (int s = 0; s < 16; s++) {
      h[s] = h[s] * expf(delta * Av[s]) + du * sP[16 + s];
      yv += h[s] * sP[32 + s];
    }
    yv += u * Dd;
    float sz = z / (1.f + expf(-z));
    yb[(size_t)t * 1024] = yv * sz;
    __syncthreads();
  }
}

// ---------------- final LN + head dot + sigmoid ----------------
__global__ void head_kernel(const float* __restrict__ h, const float* __restrict__ g,
                            const float* __restrict__ bv, const float* __restrict__ hw,
                            const float* __restrict__ hb, float* __restrict__ out) {
  int token = blockIdx.x;
  int d = threadIdx.x;
  float v = h[(size_t)token * DM + d];
  float s = v, q = v * v;
#pragma unroll
  for (int off = 32; off > 0; off >>= 1) {
    s += __shfl_down(s, off, 64);
    q += __shfl_down(q, off, 64);
  }
  __shared__ float ss[4], qq[4], cc[4];
  int lane = d & 63, wid = d >> 6;
  if (lane == 0) { ss[wid] = s; qq[wid] = q; }
  __syncthreads();
  s = ss[0] + ss[1] + ss[2] + ss[3];
  q = qq[0] + qq[1] + qq[2] + qq[3];
  float mu = s * (1.f / DM);
  float var = q * (1.f / DM) - mu * mu;
  float rs = rsqrtf(var + 1e-5f);
  float xn = (v - mu) * rs * g[d] + bv[d];
  float c = xn * hw[d];
#pragma unroll
  for (int off = 32; off > 0; off >>= 1) c += __shfl_down(c, off, 64);
  if (lane == 0) cc[wid] = c;
  __syncthreads();
  if (threadIdx.x == 0) {
    float t = cc[0] + cc[1] + cc[2] + cc[3] + hb[0];
    out[token] = 1.f / (1.f + expf(-t));
  }
}

extern "C" void kernel_launch(void* const* d_in, const int* in_sizes, int n_in,
                              void* d_out, int out_size, void* d_ws, size_t ws_size,
                              hipStream_t stream) {
  const float* x        = (const float*)d_in[0];
  const float* stem_w   = (const float*)d_in[1];
  const float* stem_b   = (const float*)d_in[2];
  const float* norm_g   = (const float*)d_in[3];
  const float* norm_b   = (const float*)d_in[4];
  const float* in_proj_w= (const float*)d_in[5];
  const float* conv_w   = (const float*)d_in[6];
  const float* conv_b   = (const float*)d_in[7];
  const float* x_proj_w = (const float*)d_in[8];
  const float* dt_w     = (const float*)d_in[9];
  const float* dt_b     = (const float*)d_in[10];
  const float* A_log    = (const float*)d_in[11];
  const float* Dp       = (const float*)d_in[12];
  const float* out_w    = (const float*)d_in[13];
  const float* fnorm_g  = (const float*)d_in[14];
  const float* fnorm_b  = (const float*)d_in[15];
  const float* head_w   = (const float*)d_in[16];
  const float* head_b   = (const float*)d_in[17];

  float* ws   = (float*)d_ws;
  float* h    = ws;                 // NT*DM      = 4,194,304
  float* xn   = ws + 4194304;       // NT*DM      = 4,194,304
  float* xz   = ws + 8388608;       // NT*1024    = 16,777,216
  float* xin  = ws + 25165824;      // NT*DI      = 8,388,608
  float* proj = ws + 33554432;      // NT*48      = 786,432
  // total: 34,340,864 floats = 131 MB

  stem_kernel<<<NT, 256, 0, stream>>>(x, stem_w, stem_b, h);

  for (int i = 0; i < 4; i++) {
    ln_kernel<<<NT, 256, 0, stream>>>(h, norm_g + i * DM, norm_b + i * DM, xn);

    dim3 g1(1024 / 64, NT / 64);
    gemm_tn<<<g1, 256, 0, stream>>>(xn, DM, in_proj_w + (size_t)i * 1024 * DM,
                                    xz, 1024, 1024, DM, 0);

    conv_silu_kernel<<<NT * DI / 256, 256, 0, stream>>>(xz, conv_w + i * DI * 4,
                                                        conv_b + i * DI, xin);

    dim3 g2(1, NT / 64);
    gemm_tn<<<g2, 256, 0, stream>>>(xin, DI, x_proj_w + (size_t)i * 48 * DI,
                                    proj, 48, 48, DI, 0);

    scan_kernel<<<128, 64, 0, stream>>>(xin, proj, xz,
                                        dt_w + (size_t)i * DI * 16, dt_b + i * DI,
                                        A_log + (size_t)i * DI * 16, Dp + i * DI, xz);

    dim3 g3(DM / 64, NT / 64);
    gemm_tn<<<g3, 256, 0, stream>>>(xz, 1024, out_w + (size_t)i * DM * DI,
                                    h, DM, DM, DI, 1);
  }

  head_kernel<<<NT, 256, 0, stream>>>(h, fnorm_g, fnorm_b, head_w, head_b, (float*)d_out);
}

// Round 3
// 2410.489 us; speedup vs baseline: 3.0554x; 3.0554x over previous
//
#include <hip/hip_runtime.h>
#include <math.h>

#define BSZ 16
#define LQ 1024
#define DM 256
#define DI 512
#define NT (BSZ*LQ)   // 16384 tokens

// ---------------- stem: conv1d(k=3,pad=1) + bias + relu, output (B,L,DM) ----------------
__global__ void stem_kernel(const float* __restrict__ x, const float* __restrict__ w,
                            const float* __restrict__ bias, float* __restrict__ h) {
  int idx = blockIdx.x * 256 + threadIdx.x;   // over NT*DM = 4M
  int d = idx & 255;
  int l = (idx >> 8) & 1023;
  int b = idx >> 18;
  float acc = bias[d];
#pragma unroll
  for (int c = 0; c < 3; c++) {
    const float* xr = x + (size_t)(b * 3 + c) * LQ;
    const float* wr = w + (size_t)(d * 3 + c) * 3;
#pragma unroll
    for (int k = 0; k < 3; k++) {
      int t = l + k - 1;
      if (t >= 0 && t < LQ) acc += xr[t] * wr[k];
    }
  }
  h[idx] = fmaxf(acc, 0.f);
}

// ---------------- layernorm over DM=256, one block per token ----------------
__global__ void ln_kernel(const float* __restrict__ x, const float* __restrict__ g,
                          const float* __restrict__ bv, float* __restrict__ o) {
  int token = blockIdx.x;
  int d = threadIdx.x;
  float v = x[(size_t)token * DM + d];
  float s = v, q = v * v;
#pragma unroll
  for (int off = 32; off > 0; off >>= 1) {
    s += __shfl_down(s, off, 64);
    q += __shfl_down(q, off, 64);
  }
  __shared__ float ss[4], qq[4];
  int lane = d & 63, wid = d >> 6;
  if (lane == 0) { ss[wid] = s; qq[wid] = q; }
  __syncthreads();
  s = ss[0] + ss[1] + ss[2] + ss[3];
  q = qq[0] + qq[1] + qq[2] + qq[3];
  float mu = s * (1.f / DM);
  float var = q * (1.f / DM) - mu * mu;
  float rs = rsqrtf(var + 1e-5f);
  o[(size_t)token * DM + d] = (v - mu) * rs * g[d] + bv[d];
}

// ---------------- generic fp32 GEMM: C[M,N] (+)= A[M,K(lda)] * W[N,K]^T ----------------
__global__ void gemm_tn(const float* __restrict__ A, int lda,
                        const float* __restrict__ W,
                        float* __restrict__ C, int ldc,
                        int N, int K, int accum) {
  __shared__ float As[16][65];
  __shared__ float Ws[16][65];
  int tid = threadIdx.x;
  int bm = blockIdx.y * 64, bn = blockIdx.x * 64;
  int lm = tid >> 2;          // 0..63
  int lk = (tid & 3) << 2;    // 0,4,8,12
  int tx = tid & 15, ty = tid >> 4;
  float acc[4][4];
#pragma unroll
  for (int i = 0; i < 4; i++)
#pragma unroll
    for (int j = 0; j < 4; j++) acc[i][j] = 0.f;

  for (int k0 = 0; k0 < K; k0 += 16) {
    float4 av = *(const float4*)(A + (size_t)(bm + lm) * lda + k0 + lk);
    float4 wv = make_float4(0.f, 0.f, 0.f, 0.f);
    int wn = bn + lm;
    if (wn < N) wv = *(const float4*)(W + (size_t)wn * K + k0 + lk);
    As[lk + 0][lm] = av.x; As[lk + 1][lm] = av.y; As[lk + 2][lm] = av.z; As[lk + 3][lm] = av.w;
    Ws[lk + 0][lm] = wv.x; Ws[lk + 1][lm] = wv.y; Ws[lk + 2][lm] = wv.z; Ws[lk + 3][lm] = wv.w;
    __syncthreads();
#pragma unroll
    for (int k = 0; k < 16; k++) {
      float a[4], bb[4];
#pragma unroll
      for (int i = 0; i < 4; i++) a[i] = As[k][ty * 4 + i];
#pragma unroll
      for (int j = 0; j < 4; j++) bb[j] = Ws[k][tx * 4 + j];
#pragma unroll
      for (int i = 0; i < 4; i++)
#pragma unroll
        for (int j = 0; j < 4; j++) acc[i][j] += a[i] * bb[j];
    }
    __syncthreads();
  }
#pragma unroll
  for (int i = 0; i < 4; i++) {
    int m = bm + ty * 4 + i;
#pragma unroll
    for (int j = 0; j < 4; j++) {
      int n = bn + tx * 4 + j;
      if (n < N) {
        float* p = C + (size_t)m * ldc + n;
        *p = (accum ? *p : 0.f) + acc[i][j];
      }
    }
  }
}

// ---------------- causal depthwise conv (k=4, left pad 3) + bias + silu ----------------
__global__ void conv_silu_kernel(const float* __restrict__ xz, const float* __restrict__ cw,
                                 const float* __restrict__ cb, float* __restrict__ xin) {
  int idx = blockIdx.x * 256 + threadIdx.x;   // over NT*DI = 8M
  int d = idx & 511;
  int l = (idx >> 9) & 1023;
  int b = idx >> 19;
  float acc = cb[d];
  const float* base = xz + (size_t)b * LQ * 1024 + d;
#pragma unroll
  for (int k = 0; k < 4; k++) {
    int t = l + k - 3;
    if (t >= 0) acc += base[(size_t)t * 1024] * cw[d * 4 + k];
  }
  xin[idx] = acc / (1.f + __expf(-acc));
}

// ---------------- 16-lane sum via DPP (VALU pipe, no LDS traffic) ----------------
template <int CTRL>
__device__ __forceinline__ float dpp_add(float x) {
  int yi = __builtin_amdgcn_update_dpp(0, __float_as_int(x), CTRL, 0xF, 0xF, true);
  return x + __int_as_float(yi);
}
__device__ __forceinline__ float sum16(float x) {
  x = dpp_add<0xB1>(x);   // quad_perm [1,0,3,2]  (xor 1)
  x = dpp_add<0x4E>(x);   // quad_perm [2,3,0,1]  (xor 2)
  x = dpp_add<0x124>(x);  // row_ror:4
  x = dpp_add<0x128>(x);  // row_ror:8
  return x;               // all 16 lanes of the row hold the sum
}

// ---------------- fused delta-proj + selective scan + Dp skip + silu(z) gate ----------------
// 16 lanes per (b,d) chain (one per state). Block = 256 threads = 16 chains (one b,
// 16 consecutive d). Grid = 16 b * 32 groups = 512 blocks. Time chunked by 16 steps:
// proj/u/z staged coalesced in LDS, delta for the 16 steps computed in parallel,
// y staged in LDS and written back coalesced. y goes into x-half of xz (stride 1024).
#define TCH 16
__global__ __launch_bounds__(256) void scan_kernel(
    const float* __restrict__ xin, const float* __restrict__ proj,
    const float* __restrict__ xz,
    const float* __restrict__ dt_w, const float* __restrict__ dt_b,
    const float* __restrict__ A_log, const float* __restrict__ Dp,
    float* __restrict__ yout) {
  int b  = blockIdx.x >> 5;          // 0..15
  int d0 = (blockIdx.x & 31) << 4;   // 0,16,...,496
  int tid = threadIdx.x;
  int ci = tid >> 4;   // chain within block (0..15)
  int s  = tid & 15;   // state index (0..15)
  int d = d0 + ci;

  __shared__ float sProj[TCH * 49];   // padded stride 49 (bank-conflict-free delta dot)
  __shared__ float sU[TCH * 16];      // [t][d_local]
  __shared__ float sZ[TCH * 16];      // [t][d_local]
  __shared__ float sDelta[16 * TCH];  // [ci][t]
  __shared__ float sY[TCH * 16];      // [t][d_local]

  float Av = -__expf(A_log[(size_t)d * 16 + s]);
  float wv[16];
#pragma unroll
  for (int r = 0; r < 16; r++) wv[r] = dt_w[(size_t)d * 16 + r];
  float db = dt_b[d], Dd = Dp[d];
  float h = 0.f;

  const float* projb = proj + (size_t)b * LQ * 48;
  const float* xinb  = xin  + (size_t)b * LQ * 512 + d0;
  const float* zb    = xz   + (size_t)b * LQ * 1024 + 512 + d0;
  float* yb          = yout + (size_t)b * LQ * 1024 + d0;

  int tt = tid >> 4, j = tid & 15;   // for cooperative load/store (same as ci,s)

  for (int t0 = 0; t0 < LQ; t0 += TCH) {
    // ---- stage chunk into LDS (coalesced) ----
    {
      const float* g = projb + t0 * 48;
#pragma unroll
      for (int k = 0; k < 3; k++) {
        int idx = tid + k * 256;          // 0..767
        int tr = idx / 48, rr = idx - tr * 48;
        sProj[tr * 49 + rr] = g[idx];
      }
      sU[tid] = xinb[(size_t)(t0 + tt) * 512 + j];
      sZ[tid] = zb[(size_t)(t0 + tt) * 1024 + j];
    }
    __syncthreads();

    // ---- delta for all 16 steps in parallel: thread = (chain ci, t = s) ----
    {
      float dt = db;
#pragma unroll
      for (int r = 0; r < 16; r++) dt += sProj[s * 49 + r] * wv[r];
      float delta = (dt > 15.f) ? dt : __logf(1.f + __expf(dt));
      sDelta[ci * 16 + s] = delta;
    }
    __syncthreads();

    // ---- sequential scan over the 16 steps ----
#pragma unroll
    for (int t = 0; t < TCH; t++) {
      float delta = sDelta[ci * 16 + t];
      float u  = sU[t * 16 + ci];
      float e  = __expf(delta * Av);
      float Bt = sProj[t * 49 + 16 + s];
      float Ct = sProj[t * 49 + 32 + s];
      h = h * e + (delta * u) * Bt;
      float p = sum16(h * Ct);
      if (s == 0) {
        float z = sZ[t * 16 + ci];
        float y = p + u * Dd;
        float sz = z / (1.f + __expf(-z));
        sY[t * 16 + ci] = y * sz;
      }
    }
    __syncthreads();

    // ---- coalesced writeback ----
    yb[(size_t)(t0 + tt) * 1024 + j] = sY[tt * 16 + j];
    __syncthreads();
  }
}

// ---------------- final LN + head dot + sigmoid ----------------
__global__ void head_kernel(const float* __restrict__ h, const float* __restrict__ g,
                            const float* __restrict__ bv, const float* __restrict__ hw,
                            const float* __restrict__ hb, float* __restrict__ out) {
  int token = blockIdx.x;
  int d = threadIdx.x;
  float v = h[(size_t)token * DM + d];
  float s = v, q = v * v;
#pragma unroll
  for (int off = 32; off > 0; off >>= 1) {
    s += __shfl_down(s, off, 64);
    q += __shfl_down(q, off, 64);
  }
  __shared__ float ss[4], qq[4], cc[4];
  int lane = d & 63, wid = d >> 6;
  if (lane == 0) { ss[wid] = s; qq[wid] = q; }
  __syncthreads();
  s = ss[0] + ss[1] + ss[2] + ss[3];
  q = qq[0] + qq[1] + qq[2] + qq[3];
  float mu = s * (1.f / DM);
  float var = q * (1.f / DM) - mu * mu;
  float rs = rsqrtf(var + 1e-5f);
  float xn = (v - mu) * rs * g[d] + bv[d];
  float c = xn * hw[d];
#pragma unroll
  for (int off = 32; off > 0; off >>= 1) c += __shfl_down(c, off, 64);
  if (lane == 0) cc[wid] = c;
  __syncthreads();
  if (threadIdx.x == 0) {
    float t = cc[0] + cc[1] + cc[2] + cc[3] + hb[0];
    out[token] = 1.f / (1.f + __expf(-t));
  }
}

extern "C" void kernel_launch(void* const* d_in, const int* in_sizes, int n_in,
                              void* d_out, int out_size, void* d_ws, size_t ws_size,
                              hipStream_t stream) {
  const float* x        = (const float*)d_in[0];
  const float* stem_w   = (const float*)d_in[1];
  const float* stem_b   = (const float*)d_in[2];
  const float* norm_g   = (const float*)d_in[3];
  const float* norm_b   = (const float*)d_in[4];
  const float* in_proj_w= (const float*)d_in[5];
  const float* conv_w   = (const float*)d_in[6];
  const float* conv_b   = (const float*)d_in[7];
  const float* x_proj_w = (const float*)d_in[8];
  const float* dt_w     = (const float*)d_in[9];
  const float* dt_b     = (const float*)d_in[10];
  const float* A_log    = (const float*)d_in[11];
  const float* Dp       = (const float*)d_in[12];
  const float* out_w    = (const float*)d_in[13];
  const float* fnorm_g  = (const float*)d_in[14];
  const float* fnorm_b  = (const float*)d_in[15];
  const float* head_w   = (const float*)d_in[16];
  const float* head_b   = (const float*)d_in[17];

  float* ws   = (float*)d_ws;
  float* h    = ws;                 // NT*DM      = 4,194,304
  float* xn   = ws + 4194304;       // NT*DM      = 4,194,304
  float* xz   = ws + 8388608;       // NT*1024    = 16,777,216
  float* xin  = ws + 25165824;      // NT*DI      = 8,388,608
  float* proj = ws + 33554432;      // NT*48      = 786,432

  stem_kernel<<<NT, 256, 0, stream>>>(x, stem_w, stem_b, h);

  for (int i = 0; i < 4; i++) {
    ln_kernel<<<NT, 256, 0, stream>>>(h, norm_g + i * DM, norm_b + i * DM, xn);

    dim3 g1(1024 / 64, NT / 64);
    gemm_tn<<<g1, 256, 0, stream>>>(xn, DM, in_proj_w + (size_t)i * 1024 * DM,
                                    xz, 1024, 1024, DM, 0);

    conv_silu_kernel<<<NT * DI / 256, 256, 0, stream>>>(xz, conv_w + i * DI * 4,
                                                        conv_b + i * DI, xin);

    dim3 g2(1, NT / 64);
    gemm_tn<<<g2, 256, 0, stream>>>(xin, DI, x_proj_w + (size_t)i * 48 * DI,
                                    proj, 48, 48, DI, 0);

    scan_kernel<<<512, 256, 0, stream>>>(xin, proj, xz,
                                         dt_w + (size_t)i * DI * 16, dt_b + i * DI,
                                         A_log + (size_t)i * DI * 16, Dp + i * DI, xz);

    dim3 g3(DM / 64, NT / 64);
    gemm_tn<<<g3, 256, 0, stream>>>(xz, 1024, out_w + (size_t)i * DM * DI,
                                    h, DM, DM, DI, 1);
  }

  head_kernel<<<NT, 256, 0, stream>>>(h, fnorm_g, fnorm_b, head_w, head_b, (float*)d_out);
}

// Round 4
// 1473.259 us; speedup vs baseline: 4.9991x; 1.6362x over previous
//
#include <hip/hip_runtime.h>
#include <math.h>

#define BSZ 16
#define LQ 1024
#define DM 256
#define DI 512
#define NT (BSZ*LQ)   // 16384 tokens

typedef __attribute__((ext_vector_type(8))) short short8;
typedef __attribute__((ext_vector_type(4))) float f32x4;

#define AS1(p) (const __attribute__((address_space(1))) void*)(p)
#define AS3(p) (__attribute__((address_space(3))) void*)(p)
#define GLOAD16(g, l) __builtin_amdgcn_global_load_lds(AS1(g), AS3(l), 16, 0, 0)

__device__ __forceinline__ short f2bf(float f) {
  union { float f; unsigned u; } a; a.f = f;
  unsigned r = (a.u + 0x7FFF + ((a.u >> 16) & 1)) >> 16;
  return (short)r;
}
__device__ __forceinline__ float bf2f(short s) {
  union { unsigned u; float f; } a; a.u = ((unsigned)(unsigned short)s) << 16;
  return a.f;
}

// ---------------- stem: conv1d(k=3,pad=1) + bias + relu, output (B,L,DM) fp32 ----------------
__global__ void stem_kernel(const float* __restrict__ x, const float* __restrict__ w,
                            const float* __restrict__ bias, float* __restrict__ h) {
  int idx = blockIdx.x * 256 + threadIdx.x;   // over NT*DM = 4M
  int d = idx & 255;
  int l = (idx >> 8) & 1023;
  int b = idx >> 18;
  float acc = bias[d];
#pragma unroll
  for (int c = 0; c < 3; c++) {
    const float* xr = x + (size_t)(b * 3 + c) * LQ;
    const float* wr = w + (size_t)(d * 3 + c) * 3;
#pragma unroll
    for (int k = 0; k < 3; k++) {
      int t = l + k - 1;
      if (t >= 0 && t < LQ) acc += xr[t] * wr[k];
    }
  }
  h[idx] = fmaxf(acc, 0.f);
}

// ---------------- weight conversion fp32 -> bf16 (x_proj padded to 128 rows) ----------------
#define WB_IN 262144          // 1024*256
#define WB_XP 65536           // 128*512 (rows >=48 zero)
#define WB_OUT 131072         // 256*512
#define WB_L (WB_IN + WB_XP + WB_OUT)  // 458752

__global__ void convert_w(const float* __restrict__ in_w, const float* __restrict__ xp_w,
                          const float* __restrict__ out_w, short* __restrict__ wb) {
  int layer = blockIdx.y;
  int idx = blockIdx.x * 256 + threadIdx.x;
  short* dst = wb + (size_t)layer * WB_L;
  float v;
  if (idx < WB_IN) {
    v = in_w[(size_t)layer * WB_IN + idx];
  } else if (idx < WB_IN + WB_XP) {
    int k = idx - WB_IN; int row = k >> 9, col = k & 511;
    v = (row < 48) ? xp_w[(size_t)layer * 48 * 512 + row * 512 + col] : 0.f;
  } else {
    int k = idx - WB_IN - WB_XP;
    v = out_w[(size_t)layer * WB_OUT + k];
  }
  dst[idx] = f2bf(v);
}

// ---------------- layernorm over DM=256 -> bf16 out ----------------
__global__ void ln_kernel(const float* __restrict__ x, const float* __restrict__ g,
                          const float* __restrict__ bv, short* __restrict__ o) {
  int token = blockIdx.x;
  int d = threadIdx.x;
  float v = x[(size_t)token * DM + d];
  float s = v, q = v * v;
#pragma unroll
  for (int off = 32; off > 0; off >>= 1) {
    s += __shfl_down(s, off, 64);
    q += __shfl_down(q, off, 64);
  }
  __shared__ float ss[4], qq[4];
  int lane = d & 63, wid = d >> 6;
  if (lane == 0) { ss[wid] = s; qq[wid] = q; }
  __syncthreads();
  s = ss[0] + ss[1] + ss[2] + ss[3];
  q = qq[0] + qq[1] + qq[2] + qq[3];
  float mu = s * (1.f / DM);
  float var = q * (1.f / DM) - mu * mu;
  float rs = rsqrtf(var + 1e-5f);
  o[(size_t)token * DM + d] = f2bf((v - mu) * rs * g[d] + bv[d]);
}

// ---------------- bf16 MFMA GEMM: C[M,N](fp32) (+)= A[M,K](bf16) * W[N,K]^T(bf16) ----------------
// 128x128 tile, BK=32, 256 thr = 4 waves (2x2), each wave 64x64 via 4x4 cells of 16x16x32.
// Store split: col<split -> C0(ld0), else C1(ld1, col-split). col<N predicate.
__global__ __launch_bounds__(256) void gemm_mfma(
    const short* __restrict__ A, int K,
    const short* __restrict__ W,
    float* __restrict__ C0, int ld0,
    float* __restrict__ C1, int ld1,
    int split, int N, int accum) {
  __shared__ short As[128 * 32];
  __shared__ short Bs[128 * 32];
  int tid = threadIdx.x;
  int wave = tid >> 6, lane = tid & 63;
  int bm = blockIdx.y * 128, bn = blockIdx.x * 128;
  int wm = (wave >> 1) * 64, wn = (wave & 1) * 64;

  f32x4 acc[4][4];
#pragma unroll
  for (int i = 0; i < 4; i++)
#pragma unroll
    for (int j = 0; j < 4; j++) { acc[i][j][0] = 0.f; acc[i][j][1] = 0.f; acc[i][j][2] = 0.f; acc[i][j][3] = 0.f; }

  int srow = lane >> 2;          // 0..15
  int scol = (lane & 3) * 8;     // element offset within 32
  const short* Ag = A + (size_t)(bm + wave * 32 + srow) * K + scol;
  const short* Wg = W + (size_t)(bn + wave * 32 + srow) * K + scol;
  short* AsW = As + wave * 32 * 32;
  short* BsW = Bs + wave * 32 * 32;

  int fr = lane & 15;            // m/n within 16
  int kg = (lane >> 4) * 8;      // k-group offset

  for (int k0 = 0; k0 < K; k0 += 32) {
    GLOAD16(Ag + k0,                    AsW);
    GLOAD16(Ag + k0 + (size_t)16 * K,   AsW + 16 * 32);
    GLOAD16(Wg + k0,                    BsW);
    GLOAD16(Wg + k0 + (size_t)16 * K,   BsW + 16 * 32);
    __syncthreads();

    short8 af[4], bf[4];
#pragma unroll
    for (int i = 0; i < 4; i++) af[i] = *(const short8*)&As[(wm + i * 16 + fr) * 32 + kg];
#pragma unroll
    for (int j = 0; j < 4; j++) bf[j] = *(const short8*)&Bs[(wn + j * 16 + fr) * 32 + kg];
#pragma unroll
    for (int i = 0; i < 4; i++)
#pragma unroll
      for (int j = 0; j < 4; j++)
        acc[i][j] = __builtin_amdgcn_mfma_f32_16x16x32_bf16(af[i], bf[j], acc[i][j], 0, 0, 0);
    __syncthreads();
  }

  // C/D layout: col = lane&15, row = (lane>>4)*4 + reg
  int cn = lane & 15, cr = (lane >> 4) * 4;
#pragma unroll
  for (int i = 0; i < 4; i++) {
    int row0 = bm + wm + i * 16 + cr;
#pragma unroll
    for (int j = 0; j < 4; j++) {
      int col = bn + wn + j * 16 + cn;
      if (col < N) {
#pragma unroll
        for (int r = 0; r < 4; r++) {
          float v = acc[i][j][r];
          float* p = (col < split) ? (C0 + (size_t)(row0 + r) * ld0 + col)
                                   : (C1 + (size_t)(row0 + r) * ld1 + (col - split));
          if (accum) v += *p;
          *p = v;
        }
      }
    }
  }
}

// ---------------- causal depthwise conv (k=4) + bias + silu: xc fp32 -> xin bf16 ----------------
__global__ void conv_silu_kernel(const float* __restrict__ xc, const float* __restrict__ cw,
                                 const float* __restrict__ cb, short* __restrict__ xinb) {
  int idx = blockIdx.x * 256 + threadIdx.x;   // over NT*DI = 8M
  int d = idx & 511;
  int l = (idx >> 9) & 1023;
  int b = idx >> 19;
  float acc = cb[d];
  const float* base = xc + (size_t)b * LQ * 512 + d;
#pragma unroll
  for (int k = 0; k < 4; k++) {
    int t = l + k - 3;
    if (t >= 0) acc += base[(size_t)t * 512] * cw[d * 4 + k];
  }
  float s = acc / (1.f + __expf(-acc));
  xinb[idx] = f2bf(s);
}

// ---------------- 16-lane sum via DPP ----------------
template <int CTRL>
__device__ __forceinline__ float dpp_add(float x) {
  int yi = __builtin_amdgcn_update_dpp(0, __float_as_int(x), CTRL, 0xF, 0xF, true);
  return x + __int_as_float(yi);
}
__device__ __forceinline__ float sum16(float x) {
  x = dpp_add<0xB1>(x);   // quad_perm xor1
  x = dpp_add<0x4E>(x);   // quad_perm xor2
  x = dpp_add<0x124>(x);  // row_ror:4
  x = dpp_add<0x128>(x);  // row_ror:8
  return x;
}

// ---------------- fused delta-proj + selective scan + Dp skip + silu(z) gate ----------------
// u from bf16 xin, z from compact zc fp32, y out bf16 compact [NT,512].
#define TCH 16
__global__ __launch_bounds__(256) void scan_kernel(
    const short* __restrict__ xinb, const float* __restrict__ proj,
    const float* __restrict__ zc,
    const float* __restrict__ dt_w, const float* __restrict__ dt_b,
    const float* __restrict__ A_log, const float* __restrict__ Dp,
    short* __restrict__ ybf) {
  int b  = blockIdx.x >> 5;
  int d0 = (blockIdx.x & 31) << 4;
  int tid = threadIdx.x;
  int ci = tid >> 4;   // chain within block
  int s  = tid & 15;   // state index
  int d = d0 + ci;

  __shared__ float sProj[TCH * 49];
  __shared__ float sU[TCH * 16];
  __shared__ float sZ[TCH * 16];
  __shared__ float sDelta[16 * TCH];
  __shared__ float sY[TCH * 16];

  float Av = -__expf(A_log[(size_t)d * 16 + s]);
  float wv[16];
#pragma unroll
  for (int r = 0; r < 16; r++) wv[r] = dt_w[(size_t)d * 16 + r];
  float db = dt_b[d], Dd = Dp[d];
  float h = 0.f;

  const float* projb = proj + (size_t)b * LQ * 48;
  const short* xinbb = xinb + (size_t)b * LQ * 512 + d0;
  const float* zcb   = zc   + (size_t)b * LQ * 512 + d0;
  short* ybb         = ybf  + (size_t)b * LQ * 512 + d0;

  int tt = tid >> 4, j = tid & 15;

  for (int t0 = 0; t0 < LQ; t0 += TCH) {
    {
      const float* g = projb + t0 * 48;
#pragma unroll
      for (int k = 0; k < 3; k++) {
        int idx = tid + k * 256;
        int tr = idx / 48, rr = idx - tr * 48;
        sProj[tr * 49 + rr] = g[idx];
      }
      sU[tid] = bf2f(xinbb[(size_t)(t0 + tt) * 512 + j]);
      sZ[tid] = zcb[(size_t)(t0 + tt) * 512 + j];
    }
    __syncthreads();

    // delta for all 16 steps in parallel (thread = chain ci, step s)
    {
      float dt = db;
#pragma unroll
      for (int r = 0; r < 16; r++) dt += sProj[s * 49 + r] * wv[r];
      float delta = (dt > 15.f) ? dt : __logf(1.f + __expf(dt));
      sDelta[ci * 16 + s] = delta;
    }
    __syncthreads();

    // precompute per-step e, c, u (independent, hides exp latency)
    float ee[TCH], cin[TCH], uu[TCH];
#pragma unroll
    for (int t = 0; t < TCH; t++) {
      float delta = sDelta[ci * 16 + t];
      float u = sU[t * 16 + ci];
      uu[t] = u;
      ee[t] = __expf(delta * Av);
      cin[t] = delta * u * sProj[t * 49 + 16 + s];
    }
    // serial chain: 16 back-to-back FMAs + off-chain reduce
#pragma unroll
    for (int t = 0; t < TCH; t++) {
      h = h * ee[t] + cin[t];
      float p = sum16(h * sProj[t * 49 + 32 + s]);
      if (s == 0) {
        float z = sZ[t * 16 + ci];
        float y = p + uu[t] * Dd;
        float sz = z / (1.f + __expf(-z));
        sY[t * 16 + ci] = y * sz;
      }
    }
    __syncthreads();

    ybb[(size_t)(t0 + tt) * 512 + j] = f2bf(sY[tt * 16 + j]);
    __syncthreads();
  }
}

// ---------------- final LN + head dot + sigmoid ----------------
__global__ void head_kernel(const float* __restrict__ h, const float* __restrict__ g,
                            const float* __restrict__ bv, const float* __restrict__ hw,
                            const float* __restrict__ hb, float* __restrict__ out) {
  int token = blockIdx.x;
  int d = threadIdx.x;
  float v = h[(size_t)token * DM + d];
  float s = v, q = v * v;
#pragma unroll
  for (int off = 32; off > 0; off >>= 1) {
    s += __shfl_down(s, off, 64);
    q += __shfl_down(q, off, 64);
  }
  __shared__ float ss[4], qq[4], cc[4];
  int lane = d & 63, wid = d >> 6;
  if (lane == 0) { ss[wid] = s; qq[wid] = q; }
  __syncthreads();
  s = ss[0] + ss[1] + ss[2] + ss[3];
  q = qq[0] + qq[1] + qq[2] + qq[3];
  float mu = s * (1.f / DM);
  float var = q * (1.f / DM) - mu * mu;
  float rs = rsqrtf(var + 1e-5f);
  float xn = (v - mu) * rs * g[d] + bv[d];
  float c = xn * hw[d];
#pragma unroll
  for (int off = 32; off > 0; off >>= 1) c += __shfl_down(c, off, 64);
  if (lane == 0) cc[wid] = c;
  __syncthreads();
  if (threadIdx.x == 0) {
    float t = cc[0] + cc[1] + cc[2] + cc[3] + hb[0];
    out[token] = 1.f / (1.f + __expf(-t));
  }
}

extern "C" void kernel_launch(void* const* d_in, const int* in_sizes, int n_in,
                              void* d_out, int out_size, void* d_ws, size_t ws_size,
                              hipStream_t stream) {
  const float* x        = (const float*)d_in[0];
  const float* stem_w   = (const float*)d_in[1];
  const float* stem_b   = (const float*)d_in[2];
  const float* norm_g   = (const float*)d_in[3];
  const float* norm_b   = (const float*)d_in[4];
  const float* in_proj_w= (const float*)d_in[5];
  const float* conv_w   = (const float*)d_in[6];
  const float* conv_b   = (const float*)d_in[7];
  const float* x_proj_w = (const float*)d_in[8];
  const float* dt_w     = (const float*)d_in[9];
  const float* dt_b     = (const float*)d_in[10];
  const float* A_log    = (const float*)d_in[11];
  const float* Dp       = (const float*)d_in[12];
  const float* out_w    = (const float*)d_in[13];
  const float* fnorm_g  = (const float*)d_in[14];
  const float* fnorm_b  = (const float*)d_in[15];
  const float* head_w   = (const float*)d_in[16];
  const float* head_b   = (const float*)d_in[17];

  char* base = (char*)d_ws;
  float* h    = (float*)(base);                           // 16 MB
  float* xc   = (float*)(base + ((size_t)16 << 20));      // 32 MB
  float* zc   = (float*)(base + ((size_t)48 << 20));      // 32 MB
  short* xnb  = (short*)(base + ((size_t)80 << 20));      // 8 MB
  short* xinb = (short*)(base + ((size_t)88 << 20));      // 16 MB
  short* ybf  = (short*)(base + ((size_t)104 << 20));     // 16 MB
  float* proj = (float*)(base + ((size_t)120 << 20));     // 3 MB
  short* wb   = (short*)(base + ((size_t)123 << 20));     // 3.5 MB

  stem_kernel<<<NT, 256, 0, stream>>>(x, stem_w, stem_b, h);

  dim3 gcw(WB_L / 256, 4);
  convert_w<<<gcw, 256, 0, stream>>>(in_proj_w, x_proj_w, out_w, wb);

  for (int i = 0; i < 4; i++) {
    const short* wbl = wb + (size_t)i * WB_L;

    ln_kernel<<<NT, 256, 0, stream>>>(h, norm_g + i * DM, norm_b + i * DM, xnb);

    dim3 g1(8, NT / 128);
    gemm_mfma<<<g1, 256, 0, stream>>>(xnb, 256, wbl, xc, 512, zc, 512, 512, 1024, 0);

    conv_silu_kernel<<<NT * DI / 256, 256, 0, stream>>>(xc, conv_w + i * DI * 4,
                                                        conv_b + i * DI, xinb);

    dim3 g2(1, NT / 128);
    gemm_mfma<<<g2, 256, 0, stream>>>(xinb, 512, wbl + WB_IN, proj, 48, proj, 48, 48, 48, 0);

    scan_kernel<<<512, 256, 0, stream>>>(xinb, proj, zc,
                                         dt_w + (size_t)i * DI * 16, dt_b + i * DI,
                                         A_log + (size_t)i * DI * 16, Dp + i * DI, ybf);

    dim3 g3(2, NT / 128);
    gemm_mfma<<<g3, 256, 0, stream>>>(ybf, 512, wbl + WB_IN + WB_XP, h, 256, h, 256, 256, 256, 1);
  }

  head_kernel<<<NT, 256, 0, stream>>>(h, fnorm_g, fnorm_b, head_w, head_b, (float*)d_out);
}

// Round 6
// 1288.105 us; speedup vs baseline: 5.7177x; 1.1437x over previous
//
#include <hip/hip_runtime.h>
#include <math.h>

#define BSZ 16
#define LQ 1024
#define DM 256
#define DI 512
#define NT (BSZ*LQ)   // 16384 tokens

typedef __attribute__((ext_vector_type(8))) short short8;
typedef __attribute__((ext_vector_type(4))) float f32x4;

#define AS1(p) (const __attribute__((address_space(1))) void*)(p)
#define AS3(p) (__attribute__((address_space(3))) void*)(p)
#define GLOAD16(g, l) __builtin_amdgcn_global_load_lds(AS1(g), AS3(l), 16, 0, 0)

__device__ __forceinline__ short f2bf(float f) {
  union { float f; unsigned u; } a; a.f = f;
  unsigned r = (a.u + 0x7FFF + ((a.u >> 16) & 1)) >> 16;
  return (short)r;
}
__device__ __forceinline__ float bf2f(short s) {
  union { unsigned u; float f; } a; a.u = ((unsigned)(unsigned short)s) << 16;
  return a.f;
}

// ---------------- stem: conv1d(k=3,pad=1) + bias + relu, output (B,L,DM) fp32 ----------------
__global__ void stem_kernel(const float* __restrict__ x, const float* __restrict__ w,
                            const float* __restrict__ bias, float* __restrict__ h) {
  int idx = blockIdx.x * 256 + threadIdx.x;   // over NT*DM = 4M
  int d = idx & 255;
  int l = (idx >> 8) & 1023;
  int b = idx >> 18;
  float acc = bias[d];
#pragma unroll
  for (int c = 0; c < 3; c++) {
    const float* xr = x + (size_t)(b * 3 + c) * LQ;
    const float* wr = w + (size_t)(d * 3 + c) * 3;
#pragma unroll
    for (int k = 0; k < 3; k++) {
      int t = l + k - 1;
      if (t >= 0 && t < LQ) acc += xr[t] * wr[k];
    }
  }
  h[idx] = fmaxf(acc, 0.f);
}

// ---------------- weight conversion fp32 -> bf16 (x_proj padded to 128 rows) ----------------
#define WB_IN 262144          // 1024*256
#define WB_XP 65536           // 128*512 (rows >=48 zero)
#define WB_OUT 131072         // 256*512
#define WB_L (WB_IN + WB_XP + WB_OUT)  // 458752

__global__ void convert_w(const float* __restrict__ in_w, const float* __restrict__ xp_w,
                          const float* __restrict__ out_w, short* __restrict__ wb) {
  int layer = blockIdx.y;
  int idx = blockIdx.x * 256 + threadIdx.x;
  short* dst = wb + (size_t)layer * WB_L;
  float v;
  if (idx < WB_IN) {
    v = in_w[(size_t)layer * WB_IN + idx];
  } else if (idx < WB_IN + WB_XP) {
    int k = idx - WB_IN; int row = k >> 9, col = k & 511;
    v = (row < 48) ? xp_w[(size_t)layer * 48 * 512 + row * 512 + col] : 0.f;
  } else {
    int k = idx - WB_IN - WB_XP;
    v = out_w[(size_t)layer * WB_OUT + k];
  }
  dst[idx] = f2bf(v);
}

// ---------------- layernorm over DM=256 -> bf16 out ----------------
__global__ void ln_kernel(const float* __restrict__ x, const float* __restrict__ g,
                          const float* __restrict__ bv, short* __restrict__ o) {
  int token = blockIdx.x;
  int d = threadIdx.x;
  float v = x[(size_t)token * DM + d];
  float s = v, q = v * v;
#pragma unroll
  for (int off = 32; off > 0; off >>= 1) {
    s += __shfl_down(s, off, 64);
    q += __shfl_down(q, off, 64);
  }
  __shared__ float ss[4], qq[4];
  int lane = d & 63, wid = d >> 6;
  if (lane == 0) { ss[wid] = s; qq[wid] = q; }
  __syncthreads();
  s = ss[0] + ss[1] + ss[2] + ss[3];
  q = qq[0] + qq[1] + qq[2] + qq[3];
  float mu = s * (1.f / DM);
  float var = q * (1.f / DM) - mu * mu;
  float rs = rsqrtf(var + 1e-5f);
  o[(size_t)token * DM + d] = f2bf((v - mu) * rs * g[d] + bv[d]);
}

// ---------------- bf16 MFMA GEMM: C[M,N](fp32) (+)= A[M,K](bf16) * W[N,K]^T(bf16) ----------------
__global__ __launch_bounds__(256) void gemm_mfma(
    const short* __restrict__ A, int K,
    const short* __restrict__ W,
    float* __restrict__ C0, int ld0,
    float* __restrict__ C1, int ld1,
    int split, int N, int accum) {
  __shared__ short As[128 * 32];
  __shared__ short Bs[128 * 32];
  int tid = threadIdx.x;
  int wave = tid >> 6, lane = tid & 63;
  int bm = blockIdx.y * 128, bn = blockIdx.x * 128;
  int wm = (wave >> 1) * 64, wn = (wave & 1) * 64;

  f32x4 acc[4][4];
#pragma unroll
  for (int i = 0; i < 4; i++)
#pragma unroll
    for (int j = 0; j < 4; j++) { acc[i][j][0] = 0.f; acc[i][j][1] = 0.f; acc[i][j][2] = 0.f; acc[i][j][3] = 0.f; }

  int srow = lane >> 2;
  int scol = (lane & 3) * 8;
  const short* Ag = A + (size_t)(bm + wave * 32 + srow) * K + scol;
  const short* Wg = W + (size_t)(bn + wave * 32 + srow) * K + scol;
  short* AsW = As + wave * 32 * 32;
  short* BsW = Bs + wave * 32 * 32;

  int fr = lane & 15;
  int kg = (lane >> 4) * 8;

  for (int k0 = 0; k0 < K; k0 += 32) {
    GLOAD16(Ag + k0,                    AsW);
    GLOAD16(Ag + k0 + (size_t)16 * K,   AsW + 16 * 32);
    GLOAD16(Wg + k0,                    BsW);
    GLOAD16(Wg + k0 + (size_t)16 * K,   BsW + 16 * 32);
    __syncthreads();

    short8 af[4], bf[4];
#pragma unroll
    for (int i = 0; i < 4; i++) af[i] = *(const short8*)&As[(wm + i * 16 + fr) * 32 + kg];
#pragma unroll
    for (int j = 0; j < 4; j++) bf[j] = *(const short8*)&Bs[(wn + j * 16 + fr) * 32 + kg];
#pragma unroll
    for (int i = 0; i < 4; i++)
#pragma unroll
      for (int j = 0; j < 4; j++)
        acc[i][j] = __builtin_amdgcn_mfma_f32_16x16x32_bf16(af[i], bf[j], acc[i][j], 0, 0, 0);
    __syncthreads();
  }

  int cn = lane & 15, cr = (lane >> 4) * 4;
#pragma unroll
  for (int i = 0; i < 4; i++) {
    int row0 = bm + wm + i * 16 + cr;
#pragma unroll
    for (int j = 0; j < 4; j++) {
      int col = bn + wn + j * 16 + cn;
      if (col < N) {
#pragma unroll
        for (int r = 0; r < 4; r++) {
          float v = acc[i][j][r];
          float* p = (col < split) ? (C0 + (size_t)(row0 + r) * ld0 + col)
                                   : (C1 + (size_t)(row0 + r) * ld1 + (col - split));
          if (accum) v += *p;
          *p = v;
        }
      }
    }
  }
}

// ---------------- causal depthwise conv (k=4) + bias + silu: xc fp32 -> xin bf16 ----------------
__global__ void conv_silu_kernel(const float* __restrict__ xc, const float* __restrict__ cw,
                                 const float* __restrict__ cb, short* __restrict__ xinb) {
  int idx = blockIdx.x * 256 + threadIdx.x;   // over NT*DI = 8M
  int d = idx & 511;
  int l = (idx >> 9) & 1023;
  int b = idx >> 19;
  float acc = cb[d];
  const float* base = xc + (size_t)b * LQ * 512 + d;
#pragma unroll
  for (int k = 0; k < 4; k++) {
    int t = l + k - 3;
    if (t >= 0) acc += base[(size_t)t * 512] * cw[d * 4 + k];
  }
  float s = acc / (1.f + __expf(-acc));
  xinb[idx] = f2bf(s);
}

// ---------------- 16-lane sum via DPP ----------------
template <int CTRL>
__device__ __forceinline__ float dpp_add(float x) {
  int yi = __builtin_amdgcn_update_dpp(0, __float_as_int(x), CTRL, 0xF, 0xF, true);
  return x + __int_as_float(yi);
}
__device__ __forceinline__ float sum16(float x) {
  x = dpp_add<0xB1>(x);   // quad_perm xor1
  x = dpp_add<0x4E>(x);   // quad_perm xor2
  x = dpp_add<0x124>(x);  // row_ror:4
  x = dpp_add<0x128>(x);  // row_ror:8
  return x;               // all 16 lanes of the row hold the sum
}

// ---------------- fused delta-proj + selective scan + Dp skip + silu(z) gate ----------------
// 16 lanes per (b,d) chain (one per state s). Block = 256 thr = 16 chains.
// Chunked by 16 steps. Transposed, stride-20 (b128-aligned, 2-way-bank) LDS layouts so
// every per-step operand phase is 4x ds_read_b128. Gating deferred to writeback phase.
#define TCH 16
#define ST 20   // padded stride (floats): 80B = 16B-aligned, 2-way bank alias only
__global__ __launch_bounds__(256) void scan_kernel(
    const short* __restrict__ xinb, const float* __restrict__ proj,
    const float* __restrict__ zc,
    const float* __restrict__ dt_w, const float* __restrict__ dt_b,
    const float* __restrict__ A_log, const float* __restrict__ Dp,
    short* __restrict__ ybf) {
  int b  = blockIdx.x >> 5;
  int d0 = (blockIdx.x & 31) << 4;
  int tid = threadIdx.x;
  int ci = tid >> 4;   // chain within block (0..15)
  int s  = tid & 15;   // state index (0..15)
  int d = d0 + ci;

  __shared__ float sDt[16 * ST];   // [t][r]  delta-proj input rows (padded)
  __shared__ float sBT[16 * ST];   // [s][t]  B transposed
  __shared__ float sCT[16 * ST];   // [s][t]  C transposed
  __shared__ float sUT[16 * ST];   // [j][t]  u transposed
  __shared__ float sDel[16 * 16];  // [ci][t] delta
  __shared__ float sY[16 * 16];    // [t][j]  reduced scan output

  float Av = -__expf(A_log[(size_t)d * 16 + s]);
  f32x4 wv4[4];
#pragma unroll
  for (int k = 0; k < 4; k++) wv4[k] = *(const f32x4*)&dt_w[(size_t)d * 16 + k * 4];
  float db = dt_b[d];
  float Ddj = Dp[d0 + s];          // writeback uses j == s lane mapping
  float h = 0.f;

  const float* projb = proj + (size_t)b * LQ * 48;
  const short* xinbb = xinb + (size_t)b * LQ * 512 + d0;
  const float* zcb   = zc   + (size_t)b * LQ * 512 + d0;
  short* ybb         = ybf  + (size_t)b * LQ * 512 + d0;

  int tt = tid >> 4, j = tid & 15;  // writeback/staging mapping (t=tt, chan=j)

  // staging scatter coords (hoisted)
  int tr[3], rr[3];
#pragma unroll
  for (int k = 0; k < 3; k++) { int idx = tid + k * 256; tr[k] = idx / 48; rr[k] = idx - tr[k] * 48; }

  for (int t0 = 0; t0 < LQ; t0 += TCH) {
    // ---- stage: proj (768 vals, coalesced read, scattered LDS write) + u ----
    {
      const float* g = projb + t0 * 48;
#pragma unroll
      for (int k = 0; k < 3; k++) {
        float v = g[tid + k * 256];
        int r = rr[k], t = tr[k];
        if (r < 16)      sDt[t * ST + r] = v;
        else if (r < 32) sBT[(r - 16) * ST + t] = v;
        else             sCT[(r - 32) * ST + t] = v;
      }
      // one (t,j) slot per thread: 256 threads cover 16x16
      sUT[j * ST + tt] = bf2f(xinbb[(size_t)(t0 + tt) * 512 + j]);
    }
    __syncthreads();

    // ---- delta for 16 steps in parallel: thread = (chain ci, step s) ----
    {
      f32x4 r0 = *(const f32x4*)&sDt[s * ST + 0];
      f32x4 r1 = *(const f32x4*)&sDt[s * ST + 4];
      f32x4 r2 = *(const f32x4*)&sDt[s * ST + 8];
      f32x4 r3 = *(const f32x4*)&sDt[s * ST + 12];
      float dt = db;
#pragma unroll
      for (int q = 0; q < 4; q++) {
        dt += r0[q] * wv4[0][q] + r1[q] * wv4[1][q] + r2[q] * wv4[2][q] + r3[q] * wv4[3][q];
      }
      float delta = (dt > 15.f) ? dt : __logf(1.f + __expf(dt));
      sDel[ci * 16 + s] = delta;
    }
    __syncthreads();

    // ---- precompute e_t, c_t for the chunk (vector LDS, independent exps) ----
    float ee[TCH], cin[TCH];
    {
      f32x4 dl[4], ut[4], bt[4];
#pragma unroll
      for (int k = 0; k < 4; k++) {
        dl[k] = *(const f32x4*)&sDel[ci * 16 + k * 4];
        ut[k] = *(const f32x4*)&sUT[ci * ST + k * 4];
        bt[k] = *(const f32x4*)&sBT[s * ST + k * 4];
      }
#pragma unroll
      for (int t = 0; t < TCH; t++) {
        float delta = dl[t >> 2][t & 3];
        ee[t] = __expf(delta * Av);
        cin[t] = delta * ut[t >> 2][t & 3] * bt[t >> 2][t & 3];
      }
    }

    // ---- serial chain: fma + reduce; lane s keeps step t==s ----
    {
      f32x4 ct[4];
#pragma unroll
      for (int k = 0; k < 4; k++) ct[k] = *(const f32x4*)&sCT[s * ST + k * 4];
      float pv = 0.f;
#pragma unroll
      for (int t = 0; t < TCH; t++) {
        h = h * ee[t] + cin[t];
        float p = sum16(h * ct[t >> 2][t & 3]);
        pv = (s == t) ? p : pv;
      }
      sY[s * 16 + ci] = pv;
    }
    __syncthreads();

    // ---- writeback: thread (t=tt, chan=j): y = p + u*Dp, gate silu(z), bf16 store ----
    {
      float p = sY[tt * 16 + j];
      float u = sUT[j * ST + tt];
      float z = zcb[(size_t)(t0 + tt) * 512 + j];
      float y = p + u * Ddj;
      float sz = z / (1.f + __expf(-z));
      ybb[(size_t)(t0 + tt) * 512 + j] = f2bf(y * sz);
    }
    __syncthreads();
  }
}

// ---------------- final LN + head dot + sigmoid ----------------
__global__ void head_kernel(const float* __restrict__ h, const float* __restrict__ g,
                            const float* __restrict__ bv, const float* __restrict__ hw,
                            const float* __restrict__ hb, float* __restrict__ out) {
  int token = blockIdx.x;
  int d = threadIdx.x;
  float v = h[(size_t)token * DM + d];
  float s = v, q = v * v;
#pragma unroll
  for (int off = 32; off > 0; off >>= 1) {
    s += __shfl_down(s, off, 64);
    q += __shfl_down(q, off, 64);
  }
  __shared__ float ss[4], qq[4], cc[4];
  int lane = d & 63, wid = d >> 6;
  if (lane == 0) { ss[wid] = s; qq[wid] = q; }
  __syncthreads();
  s = ss[0] + ss[1] + ss[2] + ss[3];
  q = qq[0] + qq[1] + qq[2] + qq[3];
  float mu = s * (1.f / DM);
  float var = q * (1.f / DM) - mu * mu;
  float rs = rsqrtf(var + 1e-5f);
  float xn = (v - mu) * rs * g[d] + bv[d];
  float c = xn * hw[d];
#pragma unroll
  for (int off = 32; off > 0; off >>= 1) c += __shfl_down(c, off, 64);
  if (lane == 0) cc[wid] = c;
  __syncthreads();
  if (threadIdx.x == 0) {
    float t = cc[0] + cc[1] + cc[2] + cc[3] + hb[0];
    out[token] = 1.f / (1.f + __expf(-t));
  }
}

extern "C" void kernel_launch(void* const* d_in, const int* in_sizes, int n_in,
                              void* d_out, int out_size, void* d_ws, size_t ws_size,
                              hipStream_t stream) {
  const float* x        = (const float*)d_in[0];
  const float* stem_w   = (const float*)d_in[1];
  const float* stem_b   = (const float*)d_in[2];
  const float* norm_g   = (const float*)d_in[3];
  const float* norm_b   = (const float*)d_in[4];
  const float* in_proj_w= (const float*)d_in[5];
  const float* conv_w   = (const float*)d_in[6];
  const float* conv_b   = (const float*)d_in[7];
  const float* x_proj_w = (const float*)d_in[8];
  const float* dt_w     = (const float*)d_in[9];
  const float* dt_b     = (const float*)d_in[10];
  const float* A_log    = (const float*)d_in[11];
  const float* Dp       = (const float*)d_in[12];
  const float* out_w    = (const float*)d_in[13];
  const float* fnorm_g  = (const float*)d_in[14];
  const float* fnorm_b  = (const float*)d_in[15];
  const float* head_w   = (const float*)d_in[16];
  const float* head_b   = (const float*)d_in[17];

  char* base = (char*)d_ws;
  float* h    = (float*)(base);                           // 16 MB
  float* xc   = (float*)(base + ((size_t)16 << 20));      // 32 MB
  float* zc   = (float*)(base + ((size_t)48 << 20));      // 32 MB
  short* xnb  = (short*)(base + ((size_t)80 << 20));      // 8 MB
  short* xinb = (short*)(base + ((size_t)88 << 20));      // 16 MB
  short* ybf  = (short*)(base + ((size_t)104 << 20));     // 16 MB
  float* proj = (float*)(base + ((size_t)120 << 20));     // 3 MB
  short* wb   = (short*)(base + ((size_t)123 << 20));     // 3.5 MB

  stem_kernel<<<NT, 256, 0, stream>>>(x, stem_w, stem_b, h);

  dim3 gcw(WB_L / 256, 4);
  convert_w<<<gcw, 256, 0, stream>>>(in_proj_w, x_proj_w, out_w, wb);

  for (int i = 0; i < 4; i++) {
    const short* wbl = wb + (size_t)i * WB_L;

    ln_kernel<<<NT, 256, 0, stream>>>(h, norm_g + i * DM, norm_b + i * DM, xnb);

    dim3 g1(8, NT / 128);
    gemm_mfma<<<g1, 256, 0, stream>>>(xnb, 256, wbl, xc, 512, zc, 512, 512, 1024, 0);

    conv_silu_kernel<<<NT * DI / 256, 256, 0, stream>>>(xc, conv_w + i * DI * 4,
                                                        conv_b + i * DI, xinb);

    dim3 g2(1, NT / 128);
    gemm_mfma<<<g2, 256, 0, stream>>>(xinb, 512, wbl + WB_IN, proj, 48, proj, 48, 48, 48, 0);

    scan_kernel<<<512, 256, 0, stream>>>(xinb, proj, zc,
                                         dt_w + (size_t)i * DI * 16, dt_b + i * DI,
                                         A_log + (size_t)i * DI * 16, Dp + i * DI, ybf);

    dim3 g3(2, NT / 128);
    gemm_mfma<<<g3, 256, 0, stream>>>(ybf, 512, wbl + WB_IN + WB_XP, h, 256, h, 256, 256, 256, 1);
  }

  head_kernel<<<NT, 256, 0, stream>>>(h, fnorm_g, fnorm_b, head_w, head_b, (float*)d_out);
}

// Round 7
// 1089.575 us; speedup vs baseline: 6.7595x; 1.1822x over previous
//
#include <hip/hip_runtime.h>
#include <math.h>

#define BSZ 16
#define LQ 1024
#define DM 256
#define DI 512
#define NT (BSZ*LQ)   // 16384 tokens

typedef __attribute__((ext_vector_type(8))) short short8;
typedef __attribute__((ext_vector_type(4))) float f32x4;

#define AS1(p) (const __attribute__((address_space(1))) void*)(p)
#define AS3(p) (__attribute__((address_space(3))) void*)(p)
#define GLOAD16(g, l) __builtin_amdgcn_global_load_lds(AS1(g), AS3(l), 16, 0, 0)

__device__ __forceinline__ short f2bf(float f) {
  union { float f; unsigned u; } a; a.f = f;
  unsigned r = (a.u + 0x7FFF + ((a.u >> 16) & 1)) >> 16;
  return (short)r;
}
__device__ __forceinline__ float bf2f(short s) {
  union { unsigned u; float f; } a; a.u = ((unsigned)(unsigned short)s) << 16;
  return a.f;
}

// ---------------- stem: conv1d(k=3,pad=1) + bias + relu, output (B,L,DM) fp32 ----------------
__global__ void stem_kernel(const float* __restrict__ x, const float* __restrict__ w,
                            const float* __restrict__ bias, float* __restrict__ h) {
  int idx = blockIdx.x * 256 + threadIdx.x;   // over NT*DM = 4M
  int d = idx & 255;
  int l = (idx >> 8) & 1023;
  int b = idx >> 18;
  float acc = bias[d];
#pragma unroll
  for (int c = 0; c < 3; c++) {
    const float* xr = x + (size_t)(b * 3 + c) * LQ;
    const float* wr = w + (size_t)(d * 3 + c) * 3;
#pragma unroll
    for (int k = 0; k < 3; k++) {
      int t = l + k - 1;
      if (t >= 0 && t < LQ) acc += xr[t] * wr[k];
    }
  }
  h[idx] = fmaxf(acc, 0.f);
}

// ---------------- weight conversion fp32 -> bf16 (x_proj padded to 128 rows) ----------------
#define WB_IN 262144          // 1024*256
#define WB_XP 65536           // 128*512 (rows >=48 zero)
#define WB_OUT 131072         // 256*512
#define WB_L (WB_IN + WB_XP + WB_OUT)  // 458752

__global__ void convert_w(const float* __restrict__ in_w, const float* __restrict__ xp_w,
                          const float* __restrict__ out_w, short* __restrict__ wb) {
  int layer = blockIdx.y;
  int idx = blockIdx.x * 256 + threadIdx.x;
  short* dst = wb + (size_t)layer * WB_L;
  float v;
  if (idx < WB_IN) {
    v = in_w[(size_t)layer * WB_IN + idx];
  } else if (idx < WB_IN + WB_XP) {
    int k = idx - WB_IN; int row = k >> 9, col = k & 511;
    v = (row < 48) ? xp_w[(size_t)layer * 48 * 512 + row * 512 + col] : 0.f;
  } else {
    int k = idx - WB_IN - WB_XP;
    v = out_w[(size_t)layer * WB_OUT + k];
  }
  dst[idx] = f2bf(v);
}

// ---------------- layernorm over DM=256 -> bf16 out ----------------
__global__ void ln_kernel(const float* __restrict__ x, const float* __restrict__ g,
                          const float* __restrict__ bv, short* __restrict__ o) {
  int token = blockIdx.x;
  int d = threadIdx.x;
  float v = x[(size_t)token * DM + d];
  float s = v, q = v * v;
#pragma unroll
  for (int off = 32; off > 0; off >>= 1) {
    s += __shfl_down(s, off, 64);
    q += __shfl_down(q, off, 64);
  }
  __shared__ float ss[4], qq[4];
  int lane = d & 63, wid = d >> 6;
  if (lane == 0) { ss[wid] = s; qq[wid] = q; }
  __syncthreads();
  s = ss[0] + ss[1] + ss[2] + ss[3];
  q = qq[0] + qq[1] + qq[2] + qq[3];
  float mu = s * (1.f / DM);
  float var = q * (1.f / DM) - mu * mu;
  float rs = rsqrtf(var + 1e-5f);
  o[(size_t)token * DM + d] = f2bf((v - mu) * rs * g[d] + bv[d]);
}

// ---------------- bf16 MFMA GEMM: C[M,N](fp32) (+)= A[M,K](bf16) * W[N,K]^T(bf16) ----------------
__global__ __launch_bounds__(256) void gemm_mfma(
    const short* __restrict__ A, int K,
    const short* __restrict__ W,
    float* __restrict__ C0, int ld0,
    float* __restrict__ C1, int ld1,
    int split, int N, int accum) {
  __shared__ short As[128 * 32];
  __shared__ short Bs[128 * 32];
  int tid = threadIdx.x;
  int wave = tid >> 6, lane = tid & 63;
  int bm = blockIdx.y * 128, bn = blockIdx.x * 128;
  int wm = (wave >> 1) * 64, wn = (wave & 1) * 64;

  f32x4 acc[4][4];
#pragma unroll
  for (int i = 0; i < 4; i++)
#pragma unroll
    for (int j = 0; j < 4; j++) { acc[i][j][0] = 0.f; acc[i][j][1] = 0.f; acc[i][j][2] = 0.f; acc[i][j][3] = 0.f; }

  int srow = lane >> 2;
  int scol = (lane & 3) * 8;
  const short* Ag = A + (size_t)(bm + wave * 32 + srow) * K + scol;
  const short* Wg = W + (size_t)(bn + wave * 32 + srow) * K + scol;
  short* AsW = As + wave * 32 * 32;
  short* BsW = Bs + wave * 32 * 32;

  int fr = lane & 15;
  int kg = (lane >> 4) * 8;

  for (int k0 = 0; k0 < K; k0 += 32) {
    GLOAD16(Ag + k0,                    AsW);
    GLOAD16(Ag + k0 + (size_t)16 * K,   AsW + 16 * 32);
    GLOAD16(Wg + k0,                    BsW);
    GLOAD16(Wg + k0 + (size_t)16 * K,   BsW + 16 * 32);
    __syncthreads();

    short8 af[4], bf[4];
#pragma unroll
    for (int i = 0; i < 4; i++) af[i] = *(const short8*)&As[(wm + i * 16 + fr) * 32 + kg];
#pragma unroll
    for (int j = 0; j < 4; j++) bf[j] = *(const short8*)&Bs[(wn + j * 16 + fr) * 32 + kg];
#pragma unroll
    for (int i = 0; i < 4; i++)
#pragma unroll
      for (int j = 0; j < 4; j++)
        acc[i][j] = __builtin_amdgcn_mfma_f32_16x16x32_bf16(af[i], bf[j], acc[i][j], 0, 0, 0);
    __syncthreads();
  }

  int cn = lane & 15, cr = (lane >> 4) * 4;
#pragma unroll
  for (int i = 0; i < 4; i++) {
    int row0 = bm + wm + i * 16 + cr;
#pragma unroll
    for (int j = 0; j < 4; j++) {
      int col = bn + wn + j * 16 + cn;
      if (col < N) {
#pragma unroll
        for (int r = 0; r < 4; r++) {
          float v = acc[i][j][r];
          float* p = (col < split) ? (C0 + (size_t)(row0 + r) * ld0 + col)
                                   : (C1 + (size_t)(row0 + r) * ld1 + (col - split));
          if (accum) v += *p;
          *p = v;
        }
      }
    }
  }
}

// ---------------- causal depthwise conv (k=4) + bias + silu: xc fp32 -> xin bf16 ----------------
__global__ void conv_silu_kernel(const float* __restrict__ xc, const float* __restrict__ cw,
                                 const float* __restrict__ cb, short* __restrict__ xinb) {
  int idx = blockIdx.x * 256 + threadIdx.x;   // over NT*DI = 8M
  int d = idx & 511;
  int l = (idx >> 9) & 1023;
  int b = idx >> 19;
  float acc = cb[d];
  const float* base = xc + (size_t)b * LQ * 512 + d;
#pragma unroll
  for (int k = 0; k < 4; k++) {
    int t = l + k - 3;
    if (t >= 0) acc += base[(size_t)t * 512] * cw[d * 4 + k];
  }
  float s = acc / (1.f + __expf(-acc));
  xinb[idx] = f2bf(s);
}

// ---------------- 16-lane sum via DPP ----------------
template <int CTRL>
__device__ __forceinline__ float dpp_add(float x) {
  int yi = __builtin_amdgcn_update_dpp(0, __float_as_int(x), CTRL, 0xF, 0xF, true);
  return x + __int_as_float(yi);
}
__device__ __forceinline__ float sum16(float x) {
  x = dpp_add<0xB1>(x);   // quad_perm xor1
  x = dpp_add<0x4E>(x);   // quad_perm xor2
  x = dpp_add<0x124>(x);  // row_ror:4
  x = dpp_add<0x128>(x);  // row_ror:8
  return x;               // all 16 lanes of the row hold the sum
}

// ---------------- fused delta-proj + selective scan + Dp skip + silu(z) gate ----------------
// Software-pipelined: chunk k+1's global data (proj, u, z) prefetched into REGISTERS at
// iteration top, written to (single-buffered) LDS at iteration tail. z and writeback-u
// stay in registers (staging thread == writeback thread). 3 barriers/chunk.
#define TCH 16
#define ST 20   // padded stride (floats): 80B = 16B-aligned, 2-way bank alias only (free)
__global__ __launch_bounds__(256) void scan_kernel(
    const short* __restrict__ xinb, const float* __restrict__ proj,
    const float* __restrict__ zc,
    const float* __restrict__ dt_w, const float* __restrict__ dt_b,
    const float* __restrict__ A_log, const float* __restrict__ Dp,
    short* __restrict__ ybf) {
  int b  = blockIdx.x >> 5;
  int d0 = (blockIdx.x & 31) << 4;
  int tid = threadIdx.x;
  int ci = tid >> 4;   // chain within block (0..15)
  int s  = tid & 15;   // state index (0..15)
  int d = d0 + ci;

  __shared__ float sDt[16 * ST];   // [t][r]  delta-proj input rows (padded)
  __shared__ float sBT[16 * ST];   // [s][t]  B transposed
  __shared__ float sCT[16 * ST];   // [s][t]  C transposed
  __shared__ float sUT[16 * ST];   // [j][t]  u transposed
  __shared__ float sDel[16 * 16];  // [ci][t] delta
  __shared__ float sY[16 * 16];    // [t][j]  reduced scan output

  float Av = -__expf(A_log[(size_t)d * 16 + s]);
  f32x4 wv4[4];
#pragma unroll
  for (int k = 0; k < 4; k++) wv4[k] = *(const f32x4*)&dt_w[(size_t)d * 16 + k * 4];
  float db = dt_b[d];
  float Ddj = Dp[d0 + s];          // writeback uses j == s lane mapping
  float h = 0.f;

  const float* projb = proj + (size_t)b * LQ * 48;
  const short* xinbb = xinb + (size_t)b * LQ * 512 + d0;
  const float* zcb   = zc   + (size_t)b * LQ * 512 + d0;
  short* ybb         = ybf  + (size_t)b * LQ * 512 + d0;

  int tt = tid >> 4, j = tid & 15;  // staging/writeback mapping (t=tt, chan=j)

  // staging scatter coords (hoisted)
  int tr[3], rr[3];
#pragma unroll
  for (int k = 0; k < 3; k++) { int idx = tid + k * 256; tr[k] = idx / 48; rr[k] = idx - tr[k] * 48; }

  // ---- prologue: load + stage chunk 0 ----
  float pjv[3], uv, zv;
  {
    const float* g = projb;
    pjv[0] = g[tid]; pjv[1] = g[tid + 256]; pjv[2] = g[tid + 512];
    uv = bf2f(xinbb[(size_t)tt * 512 + j]);
    zv = zcb[(size_t)tt * 512 + j];
#pragma unroll
    for (int k = 0; k < 3; k++) {
      int r = rr[k], t = tr[k];
      if (r < 16)      sDt[t * ST + r] = pjv[k];
      else if (r < 32) sBT[(r - 16) * ST + t] = pjv[k];
      else             sCT[(r - 32) * ST + t] = pjv[k];
    }
    sUT[j * ST + tt] = uv;
  }
  __syncthreads();

  const int NCH = LQ / TCH;   // 64
  for (int c = 0; c < NCH; c++) {
    int t0 = c * TCH;

    // ---- prefetch chunk c+1 into registers (latency hidden under this chunk) ----
    float pjn[3], un = 0.f, zn = 0.f;
    if (c + 1 < NCH) {
      const float* g = projb + (t0 + TCH) * 48;
      pjn[0] = g[tid]; pjn[1] = g[tid + 256]; pjn[2] = g[tid + 512];
      un = bf2f(xinbb[(size_t)(t0 + TCH + tt) * 512 + j]);
      zn = zcb[(size_t)(t0 + TCH + tt) * 512 + j];
    }

    // ---- delta for 16 steps in parallel: thread = (chain ci, step s) ----
    {
      f32x4 r0 = *(const f32x4*)&sDt[s * ST + 0];
      f32x4 r1 = *(const f32x4*)&sDt[s * ST + 4];
      f32x4 r2 = *(const f32x4*)&sDt[s * ST + 8];
      f32x4 r3 = *(const f32x4*)&sDt[s * ST + 12];
      float dt = db;
#pragma unroll
      for (int q = 0; q < 4; q++) {
        dt += r0[q] * wv4[0][q] + r1[q] * wv4[1][q] + r2[q] * wv4[2][q] + r3[q] * wv4[3][q];
      }
      float delta = (dt > 15.f) ? dt : __logf(1.f + __expf(dt));
      sDel[ci * 16 + s] = delta;
    }
    __syncthreads();   // B1: sDel visible

    // ---- precompute e_t, c_t + serial chain + sY ----
    {
      float ee[TCH], cin[TCH];
      f32x4 dl[4], ut[4], bt[4], ct[4];
#pragma unroll
      for (int k = 0; k < 4; k++) {
        dl[k] = *(const f32x4*)&sDel[ci * 16 + k * 4];
        ut[k] = *(const f32x4*)&sUT[ci * ST + k * 4];
        bt[k] = *(const f32x4*)&sBT[s * ST + k * 4];
        ct[k] = *(const f32x4*)&sCT[s * ST + k * 4];
      }
#pragma unroll
      for (int t = 0; t < TCH; t++) {
        float delta = dl[t >> 2][t & 3];
        ee[t] = __expf(delta * Av);
        cin[t] = delta * ut[t >> 2][t & 3] * bt[t >> 2][t & 3];
      }
      float pv = 0.f;
#pragma unroll
      for (int t = 0; t < TCH; t++) {
        h = h * ee[t] + cin[t];
        float p = sum16(h * ct[t >> 2][t & 3]);
        pv = (s == t) ? p : pv;
      }
      sY[s * 16 + ci] = pv;
    }
    __syncthreads();   // B2: sY visible; all compute-phase LDS reads done

    // ---- writeback (u,z from this thread's own registers) + stage chunk c+1 ----
    {
      float p = sY[tt * 16 + j];
      float y = p + uv * Ddj;
      float sz = zv / (1.f + __expf(-zv));
      ybb[(size_t)(t0 + tt) * 512 + j] = f2bf(y * sz);
    }
    if (c + 1 < NCH) {
#pragma unroll
      for (int k = 0; k < 3; k++) {
        int r = rr[k], t = tr[k];
        if (r < 16)      sDt[t * ST + r] = pjn[k];
        else if (r < 32) sBT[(r - 16) * ST + t] = pjn[k];
        else             sCT[(r - 32) * ST + t] = pjn[k];
      }
      sUT[j * ST + tt] = un;
      uv = un; zv = zn;
    }
    __syncthreads();   // B3: staged chunk c+1 visible
  }
}

// ---------------- final LN + head dot + sigmoid ----------------
__global__ void head_kernel(const float* __restrict__ h, const float* __restrict__ g,
                            const float* __restrict__ bv, const float* __restrict__ hw,
                            const float* __restrict__ hb, float* __restrict__ out) {
  int token = blockIdx.x;
  int d = threadIdx.x;
  float v = h[(size_t)token * DM + d];
  float s = v, q = v * v;
#pragma unroll
  for (int off = 32; off > 0; off >>= 1) {
    s += __shfl_down(s, off, 64);
    q += __shfl_down(q, off, 64);
  }
  __shared__ float ss[4], qq[4], cc[4];
  int lane = d & 63, wid = d >> 6;
  if (lane == 0) { ss[wid] = s; qq[wid] = q; }
  __syncthreads();
  s = ss[0] + ss[1] + ss[2] + ss[3];
  q = qq[0] + qq[1] + qq[2] + qq[3];
  float mu = s * (1.f / DM);
  float var = q * (1.f / DM) - mu * mu;
  float rs = rsqrtf(var + 1e-5f);
  float xn = (v - mu) * rs * g[d] + bv[d];
  float c = xn * hw[d];
#pragma unroll
  for (int off = 32; off > 0; off >>= 1) c += __shfl_down(c, off, 64);
  if (lane == 0) cc[wid] = c;
  __syncthreads();
  if (threadIdx.x == 0) {
    float t = cc[0] + cc[1] + cc[2] + cc[3] + hb[0];
    out[token] = 1.f / (1.f + __expf(-t));
  }
}

extern "C" void kernel_launch(void* const* d_in, const int* in_sizes, int n_in,
                              void* d_out, int out_size, void* d_ws, size_t ws_size,
                              hipStream_t stream) {
  const float* x        = (const float*)d_in[0];
  const float* stem_w   = (const float*)d_in[1];
  const float* stem_b   = (const float*)d_in[2];
  const float* norm_g   = (const float*)d_in[3];
  const float* norm_b   = (const float*)d_in[4];
  const float* in_proj_w= (const float*)d_in[5];
  const float* conv_w   = (const float*)d_in[6];
  const float* conv_b   = (const float*)d_in[7];
  const float* x_proj_w = (const float*)d_in[8];
  const float* dt_w     = (const float*)d_in[9];
  const float* dt_b     = (const float*)d_in[10];
  const float* A_log    = (const float*)d_in[11];
  const float* Dp       = (const float*)d_in[12];
  const float* out_w    = (const float*)d_in[13];
  const float* fnorm_g  = (const float*)d_in[14];
  const float* fnorm_b  = (const float*)d_in[15];
  const float* head_w   = (const float*)d_in[16];
  const float* head_b   = (const float*)d_in[17];

  char* base = (char*)d_ws;
  float* h    = (float*)(base);                           // 16 MB
  float* xc   = (float*)(base + ((size_t)16 << 20));      // 32 MB
  float* zc   = (float*)(base + ((size_t)48 << 20));      // 32 MB
  short* xnb  = (short*)(base + ((size_t)80 << 20));      // 8 MB
  short* xinb = (short*)(base + ((size_t)88 << 20));      // 16 MB
  short* ybf  = (short*)(base + ((size_t)104 << 20));     // 16 MB
  float* proj = (float*)(base + ((size_t)120 << 20));     // 3 MB
  short* wb   = (short*)(base + ((size_t)123 << 20));     // 3.5 MB

  stem_kernel<<<NT, 256, 0, stream>>>(x, stem_w, stem_b, h);

  dim3 gcw(WB_L / 256, 4);
  convert_w<<<gcw, 256, 0, stream>>>(in_proj_w, x_proj_w, out_w, wb);

  for (int i = 0; i < 4; i++) {
    const short* wbl = wb + (size_t)i * WB_L;

    ln_kernel<<<NT, 256, 0, stream>>>(h, norm_g + i * DM, norm_b + i * DM, xnb);

    dim3 g1(8, NT / 128);
    gemm_mfma<<<g1, 256, 0, stream>>>(xnb, 256, wbl, xc, 512, zc, 512, 512, 1024, 0);

    conv_silu_kernel<<<NT * DI / 256, 256, 0, stream>>>(xc, conv_w + i * DI * 4,
                                                        conv_b + i * DI, xinb);

    dim3 g2(1, NT / 128);
    gemm_mfma<<<g2, 256, 0, stream>>>(xinb, 512, wbl + WB_IN, proj, 48, proj, 48, 48, 48, 0);

    scan_kernel<<<512, 256, 0, stream>>>(xinb, proj, zc,
                                         dt_w + (size_t)i * DI * 16, dt_b + i * DI,
                                         A_log + (size_t)i * DI * 16, Dp + i * DI, ybf);

    dim3 g3(2, NT / 128);
    gemm_mfma<<<g3, 256, 0, stream>>>(ybf, 512, wbl + WB_IN + WB_XP, h, 256, h, 256, 256, 256, 1);
  }

  head_kernel<<<NT, 256, 0, stream>>>(h, fnorm_g, fnorm_b, head_w, head_b, (float*)d_out);
}

// Round 8
// 985.573 us; speedup vs baseline: 7.4728x; 1.1055x over previous
//
#include <hip/hip_runtime.h>
#include <math.h>

#define BSZ 16
#define LQ 1024
#define DM 256
#define DI 512
#define NT (BSZ*LQ)   // 16384 tokens

typedef __attribute__((ext_vector_type(8))) short short8;
typedef __attribute__((ext_vector_type(4))) float f32x4;

#define AS1(p) (const __attribute__((address_space(1))) void*)(p)
#define AS3(p) (__attribute__((address_space(3))) void*)(p)
#define GLOAD16(g, l) __builtin_amdgcn_global_load_lds(AS1(g), AS3(l), 16, 0, 0)

__device__ __forceinline__ short f2bf(float f) {
  union { float f; unsigned u; } a; a.f = f;
  unsigned r = (a.u + 0x7FFF + ((a.u >> 16) & 1)) >> 16;
  return (short)r;
}
__device__ __forceinline__ float bf2f(short s) {
  union { unsigned u; float f; } a; a.u = ((unsigned)(unsigned short)s) << 16;
  return a.f;
}

// ---------------- stem: conv1d(k=3,pad=1) + bias + relu, output (B,L,DM) fp32 ----------------
__global__ void stem_kernel(const float* __restrict__ x, const float* __restrict__ w,
                            const float* __restrict__ bias, float* __restrict__ h) {
  int idx = blockIdx.x * 256 + threadIdx.x;   // over NT*DM = 4M
  int d = idx & 255;
  int l = (idx >> 8) & 1023;
  int b = idx >> 18;
  float acc = bias[d];
#pragma unroll
  for (int c = 0; c < 3; c++) {
    const float* xr = x + (size_t)(b * 3 + c) * LQ;
    const float* wr = w + (size_t)(d * 3 + c) * 3;
#pragma unroll
    for (int k = 0; k < 3; k++) {
      int t = l + k - 1;
      if (t >= 0 && t < LQ) acc += xr[t] * wr[k];
    }
  }
  h[idx] = fmaxf(acc, 0.f);
}

// ---------------- weight conversion fp32 -> bf16 (x_proj padded to 128 rows) ----------------
#define WB_IN 262144          // 1024*256
#define WB_XP 65536           // 128*512 (rows >=48 zero)
#define WB_OUT 131072         // 256*512
#define WB_L (WB_IN + WB_XP + WB_OUT)  // 458752

__global__ void convert_w(const float* __restrict__ in_w, const float* __restrict__ xp_w,
                          const float* __restrict__ out_w, short* __restrict__ wb) {
  int layer = blockIdx.y;
  int idx = blockIdx.x * 256 + threadIdx.x;
  short* dst = wb + (size_t)layer * WB_L;
  float v;
  if (idx < WB_IN) {
    v = in_w[(size_t)layer * WB_IN + idx];
  } else if (idx < WB_IN + WB_XP) {
    int k = idx - WB_IN; int row = k >> 9, col = k & 511;
    v = (row < 48) ? xp_w[(size_t)layer * 48 * 512 + row * 512 + col] : 0.f;
  } else {
    int k = idx - WB_IN - WB_XP;
    v = out_w[(size_t)layer * WB_OUT + k];
  }
  dst[idx] = f2bf(v);
}

// ---------------- layernorm over DM=256 -> bf16 out ----------------
__global__ void ln_kernel(const float* __restrict__ x, const float* __restrict__ g,
                          const float* __restrict__ bv, short* __restrict__ o) {
  int token = blockIdx.x;
  int d = threadIdx.x;
  float v = x[(size_t)token * DM + d];
  float s = v, q = v * v;
#pragma unroll
  for (int off = 32; off > 0; off >>= 1) {
    s += __shfl_down(s, off, 64);
    q += __shfl_down(q, off, 64);
  }
  __shared__ float ss[4], qq[4];
  int lane = d & 63, wid = d >> 6;
  if (lane == 0) { ss[wid] = s; qq[wid] = q; }
  __syncthreads();
  s = ss[0] + ss[1] + ss[2] + ss[3];
  q = qq[0] + qq[1] + qq[2] + qq[3];
  float mu = s * (1.f / DM);
  float var = q * (1.f / DM) - mu * mu;
  float rs = rsqrtf(var + 1e-5f);
  o[(size_t)token * DM + d] = f2bf((v - mu) * rs * g[d] + bv[d]);
}

// ---------------- bf16 MFMA GEMM, 128x128 tile, bf16 split store (for in_proj) ----------------
__global__ __launch_bounds__(256) void gemm_mfma_s16(
    const short* __restrict__ A, int K,
    const short* __restrict__ W,
    short* __restrict__ C0, int ld0,
    short* __restrict__ C1, int ld1,
    int split, int N) {
  __shared__ short As[128 * 32];
  __shared__ short Bs[128 * 32];
  int tid = threadIdx.x;
  int wave = tid >> 6, lane = tid & 63;
  int bm = blockIdx.y * 128, bn = blockIdx.x * 128;
  int wm = (wave >> 1) * 64, wn = (wave & 1) * 64;

  f32x4 acc[4][4];
#pragma unroll
  for (int i = 0; i < 4; i++)
#pragma unroll
    for (int j = 0; j < 4; j++) { acc[i][j][0] = 0.f; acc[i][j][1] = 0.f; acc[i][j][2] = 0.f; acc[i][j][3] = 0.f; }

  int srow = lane >> 2;
  int scol = (lane & 3) * 8;
  const short* Ag = A + (size_t)(bm + wave * 32 + srow) * K + scol;
  const short* Wg = W + (size_t)(bn + wave * 32 + srow) * K + scol;
  short* AsW = As + wave * 32 * 32;
  short* BsW = Bs + wave * 32 * 32;

  int fr = lane & 15;
  int kg = (lane >> 4) * 8;

  for (int k0 = 0; k0 < K; k0 += 32) {
    GLOAD16(Ag + k0,                    AsW);
    GLOAD16(Ag + k0 + (size_t)16 * K,   AsW + 16 * 32);
    GLOAD16(Wg + k0,                    BsW);
    GLOAD16(Wg + k0 + (size_t)16 * K,   BsW + 16 * 32);
    __syncthreads();

    short8 af[4], bf[4];
#pragma unroll
    for (int i = 0; i < 4; i++) af[i] = *(const short8*)&As[(wm + i * 16 + fr) * 32 + kg];
#pragma unroll
    for (int j = 0; j < 4; j++) bf[j] = *(const short8*)&Bs[(wn + j * 16 + fr) * 32 + kg];
#pragma unroll
    for (int i = 0; i < 4; i++)
#pragma unroll
      for (int j = 0; j < 4; j++)
        acc[i][j] = __builtin_amdgcn_mfma_f32_16x16x32_bf16(af[i], bf[j], acc[i][j], 0, 0, 0);
    __syncthreads();
  }

  int cn = lane & 15, cr = (lane >> 4) * 4;
#pragma unroll
  for (int i = 0; i < 4; i++) {
    int row0 = bm + wm + i * 16 + cr;
#pragma unroll
    for (int j = 0; j < 4; j++) {
      int col = bn + wn + j * 16 + cn;
      if (col < N) {
#pragma unroll
        for (int r = 0; r < 4; r++) {
          short* p = (col < split) ? (C0 + (size_t)(row0 + r) * ld0 + col)
                                   : (C1 + (size_t)(row0 + r) * ld1 + (col - split));
          *p = f2bf(acc[i][j][r]);
        }
      }
    }
  }
}

// ---------------- bf16 MFMA GEMM, 64x64 tile BK=64 (for small-N GEMMs), fp32 C ----------------
// 4 waves, each 32x32 via 2x2 cells of 16x16x32. Grid (N/64, M/64).
__global__ __launch_bounds__(256) void gemm_mfma64(
    const short* __restrict__ A, int K,
    const short* __restrict__ W,
    float* __restrict__ C, int ldc, int N, int accum) {
  __shared__ short As[64 * 64];
  __shared__ short Bs[64 * 64];
  int tid = threadIdx.x;
  int wave = tid >> 6, lane = tid & 63;
  int bm = blockIdx.y * 64, bn = blockIdx.x * 64;
  int wm = (wave >> 1) * 32, wn = (wave & 1) * 32;

  f32x4 acc[2][2];
#pragma unroll
  for (int i = 0; i < 2; i++)
#pragma unroll
    for (int j = 0; j < 2; j++) { acc[i][j][0] = 0.f; acc[i][j][1] = 0.f; acc[i][j][2] = 0.f; acc[i][j][3] = 0.f; }

  const short* Ag = A + (size_t)bm * K;
  const short* Wg = W + (size_t)bn * K;
  int fr = lane & 15;
  int kg = (lane >> 4) * 8;

  for (int k0 = 0; k0 < K; k0 += 64) {
#pragma unroll
    for (int i = 0; i < 2; i++) {
      int c = tid + i * 256;            // chunk id: row = c>>3, 16B-chunk = c&7
      int row = c >> 3, kk = (c & 7) * 8;
      GLOAD16(Ag + (size_t)row * K + k0 + kk, As + c * 8);
      GLOAD16(Wg + (size_t)row * K + k0 + kk, Bs + c * 8);
    }
    __syncthreads();

#pragma unroll
    for (int ks = 0; ks < 2; ks++) {
      short8 af[2], bf[2];
#pragma unroll
      for (int i = 0; i < 2; i++) af[i] = *(const short8*)&As[(wm + i * 16 + fr) * 64 + ks * 32 + kg];
#pragma unroll
      for (int j = 0; j < 2; j++) bf[j] = *(const short8*)&Bs[(wn + j * 16 + fr) * 64 + ks * 32 + kg];
#pragma unroll
      for (int i = 0; i < 2; i++)
#pragma unroll
        for (int j = 0; j < 2; j++)
          acc[i][j] = __builtin_amdgcn_mfma_f32_16x16x32_bf16(af[i], bf[j], acc[i][j], 0, 0, 0);
    }
    __syncthreads();
  }

  int cn = lane & 15, cr = (lane >> 4) * 4;
#pragma unroll
  for (int i = 0; i < 2; i++) {
    int row0 = bm + wm + i * 16 + cr;
#pragma unroll
    for (int j = 0; j < 2; j++) {
      int col = bn + wn + j * 16 + cn;
      if (col < N) {
#pragma unroll
        for (int r = 0; r < 4; r++) {
          float v = acc[i][j][r];
          float* p = C + (size_t)(row0 + r) * ldc + col;
          if (accum) v += *p;
          *p = v;
        }
      }
    }
  }
}

// ---------------- causal depthwise conv (k=4) + bias + silu: xc bf16 -> xin bf16 ----------------
__global__ void conv_silu_kernel(const short* __restrict__ xcb, const float* __restrict__ cw,
                                 const float* __restrict__ cb, short* __restrict__ xinb) {
  int idx = blockIdx.x * 256 + threadIdx.x;   // over NT*DI = 8M
  int d = idx & 511;
  int l = (idx >> 9) & 1023;
  int b = idx >> 19;
  float acc = cb[d];
  const short* base = xcb + (size_t)b * LQ * 512 + d;
#pragma unroll
  for (int k = 0; k < 4; k++) {
    int t = l + k - 3;
    if (t >= 0) acc += bf2f(base[(size_t)t * 512]) * cw[d * 4 + k];
  }
  float s = acc / (1.f + __expf(-acc));
  xinb[idx] = f2bf(s);
}

// ---------------- 16-lane sum via DPP ----------------
template <int CTRL>
__device__ __forceinline__ float dpp_add(float x) {
  int yi = __builtin_amdgcn_update_dpp(0, __float_as_int(x), CTRL, 0xF, 0xF, true);
  return x + __int_as_float(yi);
}
__device__ __forceinline__ float sum16(float x) {
  x = dpp_add<0xB1>(x);   // quad_perm xor1
  x = dpp_add<0x4E>(x);   // quad_perm xor2
  x = dpp_add<0x124>(x);  // row_ror:4
  x = dpp_add<0x128>(x);  // row_ror:8
  return x;               // all 16 lanes of the row hold the sum
}

// ---------------- fused delta-proj + selective scan + Dp skip + silu(z) gate ----------------
// Software-pipelined: chunk k+1's global data (proj, u, z) prefetched into REGISTERS at
// iteration top, written to (single-buffered) LDS at iteration tail. z and writeback-u
// stay in registers (staging thread == writeback thread). 3 barriers/chunk.
#define TCH 16
#define ST 20   // padded stride (floats): 80B = 16B-aligned, 2-way bank alias only (free)
__global__ __launch_bounds__(256) void scan_kernel(
    const short* __restrict__ xinb, const float* __restrict__ proj,
    const short* __restrict__ zc,
    const float* __restrict__ dt_w, const float* __restrict__ dt_b,
    const float* __restrict__ A_log, const float* __restrict__ Dp,
    short* __restrict__ ybf) {
  int b  = blockIdx.x >> 5;
  int d0 = (blockIdx.x & 31) << 4;
  int tid = threadIdx.x;
  int ci = tid >> 4;   // chain within block (0..15)
  int s  = tid & 15;   // state index (0..15)
  int d = d0 + ci;

  __shared__ float sDt[16 * ST];   // [t][r]  delta-proj input rows (padded)
  __shared__ float sBT[16 * ST];   // [s][t]  B transposed
  __shared__ float sCT[16 * ST];   // [s][t]  C transposed
  __shared__ float sUT[16 * ST];   // [j][t]  u transposed
  __shared__ float sDel[16 * 16];  // [ci][t] delta
  __shared__ float sY[16 * 16];    // [t][j]  reduced scan output

  float Av = -__expf(A_log[(size_t)d * 16 + s]);
  f32x4 wv4[4];
#pragma unroll
  for (int k = 0; k < 4; k++) wv4[k] = *(const f32x4*)&dt_w[(size_t)d * 16 + k * 4];
  float db = dt_b[d];
  float Ddj = Dp[d0 + s];          // writeback uses j == s lane mapping
  float h = 0.f;

  const float* projb = proj + (size_t)b * LQ * 48;
  const short* xinbb = xinb + (size_t)b * LQ * 512 + d0;
  const short* zcb   = zc   + (size_t)b * LQ * 512 + d0;
  short* ybb         = ybf  + (size_t)b * LQ * 512 + d0;

  int tt = tid >> 4, j = tid & 15;  // staging/writeback mapping (t=tt, chan=j)

  // staging scatter coords (hoisted)
  int tr[3], rr[3];
#pragma unroll
  for (int k = 0; k < 3; k++) { int idx = tid + k * 256; tr[k] = idx / 48; rr[k] = idx - tr[k] * 48; }

  // ---- prologue: load + stage chunk 0 ----
  float pjv[3], uv, zv;
  {
    const float* g = projb;
    pjv[0] = g[tid]; pjv[1] = g[tid + 256]; pjv[2] = g[tid + 512];
    uv = bf2f(xinbb[(size_t)tt * 512 + j]);
    zv = bf2f(zcb[(size_t)tt * 512 + j]);
#pragma unroll
    for (int k = 0; k < 3; k++) {
      int r = rr[k], t = tr[k];
      if (r < 16)      sDt[t * ST + r] = pjv[k];
      else if (r < 32) sBT[(r - 16) * ST + t] = pjv[k];
      else             sCT[(r - 32) * ST + t] = pjv[k];
    }
    sUT[j * ST + tt] = uv;
  }
  __syncthreads();

  const int NCH = LQ / TCH;   // 64
  for (int c = 0; c < NCH; c++) {
    int t0 = c * TCH;

    // ---- prefetch chunk c+1 into registers (latency hidden under this chunk) ----
    float pjn[3], un = 0.f, zn = 0.f;
    if (c + 1 < NCH) {
      const float* g = projb + (t0 + TCH) * 48;
      pjn[0] = g[tid]; pjn[1] = g[tid + 256]; pjn[2] = g[tid + 512];
      un = bf2f(xinbb[(size_t)(t0 + TCH + tt) * 512 + j]);
      zn = bf2f(zcb[(size_t)(t0 + TCH + tt) * 512 + j]);
    }

    // ---- delta for 16 steps in parallel: thread = (chain ci, step s) ----
    {
      f32x4 r0 = *(const f32x4*)&sDt[s * ST + 0];
      f32x4 r1 = *(const f32x4*)&sDt[s * ST + 4];
      f32x4 r2 = *(const f32x4*)&sDt[s * ST + 8];
      f32x4 r3 = *(const f32x4*)&sDt[s * ST + 12];
      float dt = db;
#pragma unroll
      for (int q = 0; q < 4; q++) {
        dt += r0[q] * wv4[0][q] + r1[q] * wv4[1][q] + r2[q] * wv4[2][q] + r3[q] * wv4[3][q];
      }
      float delta = (dt > 15.f) ? dt : __logf(1.f + __expf(dt));
      sDel[ci * 16 + s] = delta;
    }
    __syncthreads();   // B1: sDel visible

    // ---- precompute e_t, c_t + serial chain + sY ----
    {
      float ee[TCH], cin[TCH];
      f32x4 dl[4], ut[4], bt[4], ct[4];
#pragma unroll
      for (int k = 0; k < 4; k++) {
        dl[k] = *(const f32x4*)&sDel[ci * 16 + k * 4];
        ut[k] = *(const f32x4*)&sUT[ci * ST + k * 4];
        bt[k] = *(const f32x4*)&sBT[s * ST + k * 4];
        ct[k] = *(const f32x4*)&sCT[s * ST + k * 4];
      }
#pragma unroll
      for (int t = 0; t < TCH; t++) {
        float delta = dl[t >> 2][t & 3];
        ee[t] = __expf(delta * Av);
        cin[t] = delta * ut[t >> 2][t & 3] * bt[t >> 2][t & 3];
      }
      float pv = 0.f;
#pragma unroll
      for (int t = 0; t < TCH; t++) {
        h = h * ee[t] + cin[t];
        float p = sum16(h * ct[t >> 2][t & 3]);
        pv = (s == t) ? p : pv;
      }
      sY[s * 16 + ci] = pv;
    }
    __syncthreads();   // B2: sY visible; all compute-phase LDS reads done

    // ---- writeback (u,z from this thread's own registers) + stage chunk c+1 ----
    {
      float p = sY[tt * 16 + j];
      float y = p + uv * Ddj;
      float sz = zv / (1.f + __expf(-zv));
      ybb[(size_t)(t0 + tt) * 512 + j] = f2bf(y * sz);
    }
    if (c + 1 < NCH) {
#pragma unroll
      for (int k = 0; k < 3; k++) {
        int r = rr[k], t = tr[k];
        if (r < 16)      sDt[t * ST + r] = pjn[k];
        else if (r < 32) sBT[(r - 16) * ST + t] = pjn[k];
        else             sCT[(r - 32) * ST + t] = pjn[k];
      }
      sUT[j * ST + tt] = un;
      uv = un; zv = zn;
    }
    __syncthreads();   // B3: staged chunk c+1 visible
  }
}

// ---------------- final LN + head dot + sigmoid ----------------
__global__ void head_kernel(const float* __restrict__ h, const float* __restrict__ g,
                            const float* __restrict__ bv, const float* __restrict__ hw,
                            const float* __restrict__ hb, float* __restrict__ out) {
  int token = blockIdx.x;
  int d = threadIdx.x;
  float v = h[(size_t)token * DM + d];
  float s = v, q = v * v;
#pragma unroll
  for (int off = 32; off > 0; off >>= 1) {
    s += __shfl_down(s, off, 64);
    q += __shfl_down(q, off, 64);
  }
  __shared__ float ss[4], qq[4], cc[4];
  int lane = d & 63, wid = d >> 6;
  if (lane == 0) { ss[wid] = s; qq[wid] = q; }
  __syncthreads();
  s = ss[0] + ss[1] + ss[2] + ss[3];
  q = qq[0] + qq[1] + qq[2] + qq[3];
  float mu = s * (1.f / DM);
  float var = q * (1.f / DM) - mu * mu;
  float rs = rsqrtf(var + 1e-5f);
  float xn = (v - mu) * rs * g[d] + bv[d];
  float c = xn * hw[d];
#pragma unroll
  for (int off = 32; off > 0; off >>= 1) c += __shfl_down(c, off, 64);
  if (lane == 0) cc[wid] = c;
  __syncthreads();
  if (threadIdx.x == 0) {
    float t = cc[0] + cc[1] + cc[2] + cc[3] + hb[0];
    out[token] = 1.f / (1.f + __expf(-t));
  }
}

extern "C" void kernel_launch(void* const* d_in, const int* in_sizes, int n_in,
                              void* d_out, int out_size, void* d_ws, size_t ws_size,
                              hipStream_t stream) {
  const float* x        = (const float*)d_in[0];
  const float* stem_w   = (const float*)d_in[1];
  const float* stem_b   = (const float*)d_in[2];
  const float* norm_g   = (const float*)d_in[3];
  const float* norm_b   = (const float*)d_in[4];
  const float* in_proj_w= (const float*)d_in[5];
  const float* conv_w   = (const float*)d_in[6];
  const float* conv_b   = (const float*)d_in[7];
  const float* x_proj_w = (const float*)d_in[8];
  const float* dt_w     = (const float*)d_in[9];
  const float* dt_b     = (const float*)d_in[10];
  const float* A_log    = (const float*)d_in[11];
  const float* Dp       = (const float*)d_in[12];
  const float* out_w    = (const float*)d_in[13];
  const float* fnorm_g  = (const float*)d_in[14];
  const float* fnorm_b  = (const float*)d_in[15];
  const float* head_w   = (const float*)d_in[16];
  const float* head_b   = (const float*)d_in[17];

  char* base = (char*)d_ws;
  float* h    = (float*)(base);                           // 16 MB
  short* xcb  = (short*)(base + ((size_t)16 << 20));      // 16 MB
  short* zcb  = (short*)(base + ((size_t)32 << 20));      // 16 MB
  short* xnb  = (short*)(base + ((size_t)48 << 20));      // 8 MB
  short* xinb = (short*)(base + ((size_t)56 << 20));      // 16 MB
  short* ybf  = (short*)(base + ((size_t)72 << 20));      // 16 MB
  float* proj = (float*)(base + ((size_t)88 << 20));      // 3 MB
  short* wb   = (short*)(base + ((size_t)91 << 20));      // 3.5 MB

  stem_kernel<<<NT, 256, 0, stream>>>(x, stem_w, stem_b, h);

  dim3 gcw(WB_L / 256, 4);
  convert_w<<<gcw, 256, 0, stream>>>(in_proj_w, x_proj_w, out_w, wb);

  for (int i = 0; i < 4; i++) {
    const short* wbl = wb + (size_t)i * WB_L;

    ln_kernel<<<NT, 256, 0, stream>>>(h, norm_g + i * DM, norm_b + i * DM, xnb);

    dim3 g1(8, NT / 128);
    gemm_mfma_s16<<<g1, 256, 0, stream>>>(xnb, 256, wbl, xcb, 512, zcb, 512, 512, 1024);

    conv_silu_kernel<<<NT * DI / 256, 256, 0, stream>>>(xcb, conv_w + i * DI * 4,
                                                        conv_b + i * DI, xinb);

    dim3 g2(1, NT / 64);
    gemm_mfma64<<<g2, 256, 0, stream>>>(xinb, 512, wbl + WB_IN, proj, 48, 48, 0);

    scan_kernel<<<512, 256, 0, stream>>>(xinb, proj, zcb,
                                         dt_w + (size_t)i * DI * 16, dt_b + i * DI,
                                         A_log + (size_t)i * DI * 16, Dp + i * DI, ybf);

    dim3 g3(4, NT / 64);
    gemm_mfma64<<<g3, 256, 0, stream>>>(ybf, 512, wbl + WB_IN + WB_XP, h, 256, 256, 1);
  }

  head_kernel<<<NT, 256, 0, stream>>>(h, fnorm_g, fnorm_b, head_w, head_b, (float*)d_out);
}

// Round 9
// 875.266 us; speedup vs baseline: 8.4146x; 1.1260x over previous
//
#include <hip/hip_runtime.h>
#include <math.h>

#define BSZ 16
#define LQ 1024
#define DM 256
#define DI 512
#define NT (BSZ*LQ)   // 16384 tokens

typedef __attribute__((ext_vector_type(8))) short short8;
typedef __attribute__((ext_vector_type(4))) short short4v;
typedef __attribute__((ext_vector_type(4))) float f32x4;

#define AS1(p) (const __attribute__((address_space(1))) void*)(p)
#define AS3(p) (__attribute__((address_space(3))) void*)(p)
#define GLOAD16(g, l) __builtin_amdgcn_global_load_lds(AS1(g), AS3(l), 16, 0, 0)

__device__ __forceinline__ short f2bf(float f) {
  union { float f; unsigned u; } a; a.f = f;
  unsigned r = (a.u + 0x7FFF + ((a.u >> 16) & 1)) >> 16;
  return (short)r;
}
__device__ __forceinline__ float bf2f(short s) {
  union { unsigned u; float f; } a; a.u = ((unsigned)(unsigned short)s) << 16;
  return a.f;
}

// ---------------- stem: conv1d(k=3,pad=1) + bias + relu, output (B,L,DM) fp32 ----------------
__global__ void stem_kernel(const float* __restrict__ x, const float* __restrict__ w,
                            const float* __restrict__ bias, float* __restrict__ h) {
  int idx = blockIdx.x * 256 + threadIdx.x;   // over NT*DM = 4M
  int d = idx & 255;
  int l = (idx >> 8) & 1023;
  int b = idx >> 18;
  float acc = bias[d];
#pragma unroll
  for (int c = 0; c < 3; c++) {
    const float* xr = x + (size_t)(b * 3 + c) * LQ;
    const float* wr = w + (size_t)(d * 3 + c) * 3;
#pragma unroll
    for (int k = 0; k < 3; k++) {
      int t = l + k - 1;
      if (t >= 0 && t < LQ) acc += xr[t] * wr[k];
    }
  }
  h[idx] = fmaxf(acc, 0.f);
}

// ---------------- weight conversion fp32 -> bf16 (x_proj padded to 128 rows) ----------------
#define WB_IN 262144          // 1024*256
#define WB_XP 65536           // 128*512 (rows >=48 zero)
#define WB_OUT 131072         // 256*512
#define WB_L (WB_IN + WB_XP + WB_OUT)  // 458752

__global__ void convert_w(const float* __restrict__ in_w, const float* __restrict__ xp_w,
                          const float* __restrict__ out_w, short* __restrict__ wb) {
  int layer = blockIdx.y;
  int idx = blockIdx.x * 256 + threadIdx.x;
  short* dst = wb + (size_t)layer * WB_L;
  float v;
  if (idx < WB_IN) {
    v = in_w[(size_t)layer * WB_IN + idx];
  } else if (idx < WB_IN + WB_XP) {
    int k = idx - WB_IN; int row = k >> 9, col = k & 511;
    v = (row < 48) ? xp_w[(size_t)layer * 48 * 512 + row * 512 + col] : 0.f;
  } else {
    int k = idx - WB_IN - WB_XP;
    v = out_w[(size_t)layer * WB_OUT + k];
  }
  dst[idx] = f2bf(v);
}

// ---------------- layernorm over DM=256 -> bf16 out; one WAVE per token ----------------
__global__ void ln_kernel(const float* __restrict__ x, const float* __restrict__ g,
                          const float* __restrict__ bv, short* __restrict__ o) {
  int token = blockIdx.x * 4 + (threadIdx.x >> 6);
  int lane = threadIdx.x & 63;
  f32x4 v = *(const f32x4*)(x + (size_t)token * DM + lane * 4);
  float s = v[0] + v[1] + v[2] + v[3];
  float q = v[0]*v[0] + v[1]*v[1] + v[2]*v[2] + v[3]*v[3];
#pragma unroll
  for (int off = 32; off > 0; off >>= 1) {
    s += __shfl_xor(s, off, 64);
    q += __shfl_xor(q, off, 64);
  }
  float mu = s * (1.f / DM);
  float var = q * (1.f / DM) - mu * mu;
  float rs = rsqrtf(var + 1e-5f);
  f32x4 gg = *(const f32x4*)(g + lane * 4);
  f32x4 bb = *(const f32x4*)(bv + lane * 4);
  short4v ov;
#pragma unroll
  for (int k = 0; k < 4; k++) ov[k] = f2bf((v[k] - mu) * rs * gg[k] + bb[k]);
  *(short4v*)(o + (size_t)token * DM + lane * 4) = ov;
}

// ---------------- bf16 MFMA GEMM, 128x128 tile, bf16 split store (for in_proj) ----------------
__global__ __launch_bounds__(256) void gemm_mfma_s16(
    const short* __restrict__ A, int K,
    const short* __restrict__ W,
    short* __restrict__ C0, int ld0,
    short* __restrict__ C1, int ld1,
    int split, int N) {
  __shared__ short As[128 * 32];
  __shared__ short Bs[128 * 32];
  int tid = threadIdx.x;
  int wave = tid >> 6, lane = tid & 63;
  int bm = blockIdx.y * 128, bn = blockIdx.x * 128;
  int wm = (wave >> 1) * 64, wn = (wave & 1) * 64;

  f32x4 acc[4][4];
#pragma unroll
  for (int i = 0; i < 4; i++)
#pragma unroll
    for (int j = 0; j < 4; j++) { acc[i][j][0] = 0.f; acc[i][j][1] = 0.f; acc[i][j][2] = 0.f; acc[i][j][3] = 0.f; }

  int srow = lane >> 2;
  int scol = (lane & 3) * 8;
  const short* Ag = A + (size_t)(bm + wave * 32 + srow) * K + scol;
  const short* Wg = W + (size_t)(bn + wave * 32 + srow) * K + scol;
  short* AsW = As + wave * 32 * 32;
  short* BsW = Bs + wave * 32 * 32;

  int fr = lane & 15;
  int kg = (lane >> 4) * 8;

  for (int k0 = 0; k0 < K; k0 += 32) {
    GLOAD16(Ag + k0,                    AsW);
    GLOAD16(Ag + k0 + (size_t)16 * K,   AsW + 16 * 32);
    GLOAD16(Wg + k0,                    BsW);
    GLOAD16(Wg + k0 + (size_t)16 * K,   BsW + 16 * 32);
    __syncthreads();

    short8 af[4], bf[4];
#pragma unroll
    for (int i = 0; i < 4; i++) af[i] = *(const short8*)&As[(wm + i * 16 + fr) * 32 + kg];
#pragma unroll
    for (int j = 0; j < 4; j++) bf[j] = *(const short8*)&Bs[(wn + j * 16 + fr) * 32 + kg];
#pragma unroll
    for (int i = 0; i < 4; i++)
#pragma unroll
      for (int j = 0; j < 4; j++)
        acc[i][j] = __builtin_amdgcn_mfma_f32_16x16x32_bf16(af[i], bf[j], acc[i][j], 0, 0, 0);
    __syncthreads();
  }

  int cn = lane & 15, cr = (lane >> 4) * 4;
#pragma unroll
  for (int i = 0; i < 4; i++) {
    int row0 = bm + wm + i * 16 + cr;
#pragma unroll
    for (int j = 0; j < 4; j++) {
      int col = bn + wn + j * 16 + cn;
      if (col < N) {
#pragma unroll
        for (int r = 0; r < 4; r++) {
          short* p = (col < split) ? (C0 + (size_t)(row0 + r) * ld0 + col)
                                   : (C1 + (size_t)(row0 + r) * ld1 + (col - split));
          *p = f2bf(acc[i][j][r]);
        }
      }
    }
  }
}

// ---------------- bf16 MFMA GEMM, 64x64 tile BK=64 (for small-N GEMMs), fp32 C ----------------
__global__ __launch_bounds__(256) void gemm_mfma64(
    const short* __restrict__ A, int K,
    const short* __restrict__ W,
    float* __restrict__ C, int ldc, int N, int accum) {
  __shared__ short As[64 * 64];
  __shared__ short Bs[64 * 64];
  int tid = threadIdx.x;
  int wave = tid >> 6, lane = tid & 63;
  int bm = blockIdx.y * 64, bn = blockIdx.x * 64;
  int wm = (wave >> 1) * 32, wn = (wave & 1) * 32;

  f32x4 acc[2][2];
#pragma unroll
  for (int i = 0; i < 2; i++)
#pragma unroll
    for (int j = 0; j < 2; j++) { acc[i][j][0] = 0.f; acc[i][j][1] = 0.f; acc[i][j][2] = 0.f; acc[i][j][3] = 0.f; }

  const short* Ag = A + (size_t)bm * K;
  const short* Wg = W + (size_t)bn * K;
  int fr = lane & 15;
  int kg = (lane >> 4) * 8;

  for (int k0 = 0; k0 < K; k0 += 64) {
#pragma unroll
    for (int i = 0; i < 2; i++) {
      int c = tid + i * 256;            // chunk id: row = c>>3, 16B-chunk = c&7
      int row = c >> 3, kk = (c & 7) * 8;
      GLOAD16(Ag + (size_t)row * K + k0 + kk, As + c * 8);
      GLOAD16(Wg + (size_t)row * K + k0 + kk, Bs + c * 8);
    }
    __syncthreads();

#pragma unroll
    for (int ks = 0; ks < 2; ks++) {
      short8 af[2], bf[2];
#pragma unroll
      for (int i = 0; i < 2; i++) af[i] = *(const short8*)&As[(wm + i * 16 + fr) * 64 + ks * 32 + kg];
#pragma unroll
      for (int j = 0; j < 2; j++) bf[j] = *(const short8*)&Bs[(wn + j * 16 + fr) * 64 + ks * 32 + kg];
#pragma unroll
      for (int i = 0; i < 2; i++)
#pragma unroll
        for (int j = 0; j < 2; j++)
          acc[i][j] = __builtin_amdgcn_mfma_f32_16x16x32_bf16(af[i], bf[j], acc[i][j], 0, 0, 0);
    }
    __syncthreads();
  }

  int cn = lane & 15, cr = (lane >> 4) * 4;
#pragma unroll
  for (int i = 0; i < 2; i++) {
    int row0 = bm + wm + i * 16 + cr;
#pragma unroll
    for (int j = 0; j < 2; j++) {
      int col = bn + wn + j * 16 + cn;
      if (col < N) {
#pragma unroll
        for (int r = 0; r < 4; r++) {
          float v = acc[i][j][r];
          float* p = C + (size_t)(row0 + r) * ldc + col;
          if (accum) v += *p;
          *p = v;
        }
      }
    }
  }
}

// ---------------- causal depthwise conv (k=4) + bias + silu: xc bf16 -> xin bf16 ----------------
__global__ void conv_silu_kernel(const short* __restrict__ xcb, const float* __restrict__ cw,
                                 const float* __restrict__ cb, short* __restrict__ xinb) {
  int idx = blockIdx.x * 256 + threadIdx.x;   // over NT*DI = 8M
  int d = idx & 511;
  int l = (idx >> 9) & 1023;
  int b = idx >> 19;
  float acc = cb[d];
  const short* base = xcb + (size_t)b * LQ * 512 + d;
#pragma unroll
  for (int k = 0; k < 4; k++) {
    int t = l + k - 3;
    if (t >= 0) acc += bf2f(base[(size_t)t * 512]) * cw[d * 4 + k];
  }
  float s = acc / (1.f + __expf(-acc));
  xinb[idx] = f2bf(s);
}

// ---------------- 16-lane sum via DPP ----------------
template <int CTRL>
__device__ __forceinline__ float dpp_add(float x) {
  int yi = __builtin_amdgcn_update_dpp(0, __float_as_int(x), CTRL, 0xF, 0xF, true);
  return x + __int_as_float(yi);
}
__device__ __forceinline__ float sum16(float x) {
  x = dpp_add<0xB1>(x);   // quad_perm xor1
  x = dpp_add<0x4E>(x);   // quad_perm xor2
  x = dpp_add<0x124>(x);  // row_ror:4
  x = dpp_add<0x128>(x);  // row_ror:8
  return x;               // all 16 lanes of the row hold the sum
}

// ---------------- fused delta-proj + selective scan + Dp skip + silu(z) gate ----------------
// TCH=32: 3 barriers per 32 steps (was per 16). Thread (ci,s) = chain ci, state s.
// Delta phase computes 2 deltas/thread (steps s, s+16) AND du = delta*u (shared via sDU,
// removing per-lane-redundant muls). Register-pipelined prefetch of chunk c+1.
#define TCH 32
__global__ __launch_bounds__(256) void scan_kernel(
    const short* __restrict__ xinb, const float* __restrict__ proj,
    const short* __restrict__ zc,
    const float* __restrict__ dt_w, const float* __restrict__ dt_b,
    const float* __restrict__ A_log, const float* __restrict__ Dp,
    short* __restrict__ ybf) {
  int b  = blockIdx.x >> 5;
  int d0 = (blockIdx.x & 31) << 4;
  int tid = threadIdx.x;
  int ci = tid >> 4;   // chain within block (0..15)
  int s  = tid & 15;   // state index (0..15)
  int d = d0 + ci;

  __shared__ float sDt[32 * 20];   // [t][r]   delta-proj rows, stride 20 (b128-aligned)
  __shared__ float sBT[16 * 36];   // [s][t]   B transposed, stride 36 (4*ci bank spread)
  __shared__ float sCT[16 * 36];   // [s][t]   C transposed
  __shared__ float sUT[16 * 36];   // [chain][t] u
  __shared__ float sDU[16 * 36];   // [chain][t] delta*u
  __shared__ float sDel[16 * 36];  // [chain][t] delta
  __shared__ float sY[32 * 17];    // [t][chain] reduced scan output

  float Av = -__expf(A_log[(size_t)d * 16 + s]);
  f32x4 wv4[4];
#pragma unroll
  for (int k = 0; k < 4; k++) wv4[k] = *(const f32x4*)&dt_w[(size_t)d * 16 + k * 4];
  float db = dt_b[d];
  float Ddj = Dp[d0 + s];          // writeback uses j == s lane mapping
  float h = 0.f;

  const float* projb = proj + (size_t)b * LQ * 48;
  const short* xinbb = xinb + (size_t)b * LQ * 512 + d0;
  const short* zcb   = zc   + (size_t)b * LQ * 512 + d0;
  short* ybb         = ybf  + (size_t)b * LQ * 512 + d0;

  int tt = tid >> 4, j = tid & 15;  // staging/writeback mapping (t=tt / tt+16, chan=j)

  // staging scatter coords for 6 rounds (32*48 = 1536 floats)
  int tr[6], rr[6];
#pragma unroll
  for (int k = 0; k < 6; k++) { int idx = tid + k * 256; tr[k] = idx / 48; rr[k] = idx - tr[k] * 48; }

  // ---- prologue: load + stage chunk 0 ----
  float uv0, uv1, zv0, zv1;
  {
    float pjv[6];
#pragma unroll
    for (int k = 0; k < 6; k++) pjv[k] = projb[tid + k * 256];
    uv0 = bf2f(xinbb[(size_t)tt * 512 + j]);
    uv1 = bf2f(xinbb[(size_t)(tt + 16) * 512 + j]);
    zv0 = bf2f(zcb[(size_t)tt * 512 + j]);
    zv1 = bf2f(zcb[(size_t)(tt + 16) * 512 + j]);
#pragma unroll
    for (int k = 0; k < 6; k++) {
      int r = rr[k], t = tr[k];
      if (r < 16)      sDt[t * 20 + r] = pjv[k];
      else if (r < 32) sBT[(r - 16) * 36 + t] = pjv[k];
      else             sCT[(r - 32) * 36 + t] = pjv[k];
    }
    sUT[j * 36 + tt] = uv0;
    sUT[j * 36 + tt + 16] = uv1;
  }
  __syncthreads();

  const int NCH = LQ / TCH;   // 32
  for (int c = 0; c < NCH; c++) {
    int t0 = c * TCH;

    // ---- prefetch chunk c+1 into registers ----
    float pjn[6], un0 = 0.f, un1 = 0.f, zn0 = 0.f, zn1 = 0.f;
    if (c + 1 < NCH) {
      const float* g = projb + (t0 + TCH) * 48;
#pragma unroll
      for (int k = 0; k < 6; k++) pjn[k] = g[tid + k * 256];
      un0 = bf2f(xinbb[(size_t)(t0 + TCH + tt) * 512 + j]);
      un1 = bf2f(xinbb[(size_t)(t0 + TCH + tt + 16) * 512 + j]);
      zn0 = bf2f(zcb[(size_t)(t0 + TCH + tt) * 512 + j]);
      zn1 = bf2f(zcb[(size_t)(t0 + TCH + tt + 16) * 512 + j]);
    }

    // ---- delta phase: thread (ci,s) -> steps s and s+16 of chain ci ----
    {
      f32x4 a0 = *(const f32x4*)&sDt[s * 20 + 0];
      f32x4 a1 = *(const f32x4*)&sDt[s * 20 + 4];
      f32x4 a2 = *(const f32x4*)&sDt[s * 20 + 8];
      f32x4 a3 = *(const f32x4*)&sDt[s * 20 + 12];
      f32x4 b0 = *(const f32x4*)&sDt[(s + 16) * 20 + 0];
      f32x4 b1 = *(const f32x4*)&sDt[(s + 16) * 20 + 4];
      f32x4 b2 = *(const f32x4*)&sDt[(s + 16) * 20 + 8];
      f32x4 b3 = *(const f32x4*)&sDt[(s + 16) * 20 + 12];
      float dt0 = db, dt1 = db;
#pragma unroll
      for (int q = 0; q < 4; q++) {
        dt0 += a0[q] * wv4[0][q] + a1[q] * wv4[1][q] + a2[q] * wv4[2][q] + a3[q] * wv4[3][q];
        dt1 += b0[q] * wv4[0][q] + b1[q] * wv4[1][q] + b2[q] * wv4[2][q] + b3[q] * wv4[3][q];
      }
      float de0 = (dt0 > 15.f) ? dt0 : __logf(1.f + __expf(dt0));
      float de1 = (dt1 > 15.f) ? dt1 : __logf(1.f + __expf(dt1));
      float u0 = sUT[ci * 36 + s];
      float u1 = sUT[ci * 36 + s + 16];
      sDel[ci * 36 + s]      = de0;
      sDel[ci * 36 + s + 16] = de1;
      sDU[ci * 36 + s]       = de0 * u0;
      sDU[ci * 36 + s + 16]  = de1 * u1;
    }
    __syncthreads();   // B1: sDel/sDU visible

    // ---- precompute e_t, c_t for 32 steps + serial chain ----
    {
      float ee[TCH], cin[TCH];
      f32x4 ct[8];
      {
        f32x4 dl[8], du8[8], bt[8];
#pragma unroll
        for (int k = 0; k < 8; k++) {
          dl[k]  = *(const f32x4*)&sDel[ci * 36 + k * 4];
          du8[k] = *(const f32x4*)&sDU[ci * 36 + k * 4];
          bt[k]  = *(const f32x4*)&sBT[s * 36 + k * 4];
          ct[k]  = *(const f32x4*)&sCT[s * 36 + k * 4];
        }
#pragma unroll
        for (int t = 0; t < TCH; t++) {
          ee[t] = __expf(dl[t >> 2][t & 3] * Av);
          cin[t] = du8[t >> 2][t & 3] * bt[t >> 2][t & 3];
        }
      }
      float pv0 = 0.f, pv1 = 0.f;
#pragma unroll
      for (int t = 0; t < TCH; t++) {
        h = h * ee[t] + cin[t];
        float p = sum16(h * ct[t >> 2][t & 3]);
        if (t < 16) pv0 = (s == t) ? p : pv0;
        else        pv1 = (s == (t - 16)) ? p : pv1;
      }
      sY[s * 17 + ci] = pv0;
      sY[(s + 16) * 17 + ci] = pv1;
    }
    __syncthreads();   // B2: sY visible; all compute-phase LDS reads done

    // ---- writeback (u,z from registers) + stage chunk c+1 ----
    {
      float p0 = sY[tt * 17 + j];
      float p1 = sY[(tt + 16) * 17 + j];
      float y0 = p0 + uv0 * Ddj;
      float y1 = p1 + uv1 * Ddj;
      float g0 = zv0 / (1.f + __expf(-zv0));
      float g1 = zv1 / (1.f + __expf(-zv1));
      ybb[(size_t)(t0 + tt) * 512 + j] = f2bf(y0 * g0);
      ybb[(size_t)(t0 + tt + 16) * 512 + j] = f2bf(y1 * g1);
    }
    if (c + 1 < NCH) {
#pragma unroll
      for (int k = 0; k < 6; k++) {
        int r = rr[k], t = tr[k];
        if (r < 16)      sDt[t * 20 + r] = pjn[k];
        else if (r < 32) sBT[(r - 16) * 36 + t] = pjn[k];
        else             sCT[(r - 32) * 36 + t] = pjn[k];
      }
      sUT[j * 36 + tt] = un0;
      sUT[j * 36 + tt + 16] = un1;
      uv0 = un0; uv1 = un1; zv0 = zn0; zv1 = zn1;
    }
    __syncthreads();   // B3: staged chunk c+1 visible
  }
}

// ---------------- final LN + head dot + sigmoid ----------------
__global__ void head_kernel(const float* __restrict__ h, const float* __restrict__ g,
                            const float* __restrict__ bv, const float* __restrict__ hw,
                            const float* __restrict__ hb, float* __restrict__ out) {
  int token = blockIdx.x;
  int d = threadIdx.x;
  float v = h[(size_t)token * DM + d];
  float s = v, q = v * v;
#pragma unroll
  for (int off = 32; off > 0; off >>= 1) {
    s += __shfl_down(s, off, 64);
    q += __shfl_down(q, off, 64);
  }
  __shared__ float ss[4], qq[4], cc[4];
  int lane = d & 63, wid = d >> 6;
  if (lane == 0) { ss[wid] = s; qq[wid] = q; }
  __syncthreads();
  s = ss[0] + ss[1] + ss[2] + ss[3];
  q = qq[0] + qq[1] + qq[2] + qq[3];
  float mu = s * (1.f / DM);
  float var = q * (1.f / DM) - mu * mu;
  float rs = rsqrtf(var + 1e-5f);
  float xn = (v - mu) * rs * g[d] + bv[d];
  float c = xn * hw[d];
#pragma unroll
  for (int off = 32; off > 0; off >>= 1) c += __shfl_down(c, off, 64);
  if (lane == 0) cc[wid] = c;
  __syncthreads();
  if (threadIdx.x == 0) {
    float t = cc[0] + cc[1] + cc[2] + cc[3] + hb[0];
    out[token] = 1.f / (1.f + __expf(-t));
  }
}

extern "C" void kernel_launch(void* const* d_in, const int* in_sizes, int n_in,
                              void* d_out, int out_size, void* d_ws, size_t ws_size,
                              hipStream_t stream) {
  const float* x        = (const float*)d_in[0];
  const float* stem_w   = (const float*)d_in[1];
  const float* stem_b   = (const float*)d_in[2];
  const float* norm_g   = (const float*)d_in[3];
  const float* norm_b   = (const float*)d_in[4];
  const float* in_proj_w= (const float*)d_in[5];
  const float* conv_w   = (const float*)d_in[6];
  const float* conv_b   = (const float*)d_in[7];
  const float* x_proj_w = (const float*)d_in[8];
  const float* dt_w     = (const float*)d_in[9];
  const float* dt_b     = (const float*)d_in[10];
  const float* A_log    = (const float*)d_in[11];
  const float* Dp       = (const float*)d_in[12];
  const float* out_w    = (const float*)d_in[13];
  const float* fnorm_g  = (const float*)d_in[14];
  const float* fnorm_b  = (const float*)d_in[15];
  const float* head_w   = (const float*)d_in[16];
  const float* head_b   = (const float*)d_in[17];

  char* base = (char*)d_ws;
  float* h    = (float*)(base);                           // 16 MB
  short* xcb  = (short*)(base + ((size_t)16 << 20));      // 16 MB
  short* zcb  = (short*)(base + ((size_t)32 << 20));      // 16 MB
  short* xnb  = (short*)(base + ((size_t)48 << 20));      // 8 MB
  short* xinb = (short*)(base + ((size_t)56 << 20));      // 16 MB
  short* ybf  = (short*)(base + ((size_t)72 << 20));      // 16 MB
  float* proj = (float*)(base + ((size_t)88 << 20));      // 3 MB
  short* wb   = (short*)(base + ((size_t)91 << 20));      // 3.5 MB

  stem_kernel<<<NT, 256, 0, stream>>>(x, stem_w, stem_b, h);

  dim3 gcw(WB_L / 256, 4);
  convert_w<<<gcw, 256, 0, stream>>>(in_proj_w, x_proj_w, out_w, wb);

  for (int i = 0; i < 4; i++) {
    const short* wbl = wb + (size_t)i * WB_L;

    ln_kernel<<<NT / 4, 256, 0, stream>>>(h, norm_g + i * DM, norm_b + i * DM, xnb);

    dim3 g1(8, NT / 128);
    gemm_mfma_s16<<<g1, 256, 0, stream>>>(xnb, 256, wbl, xcb, 512, zcb, 512, 512, 1024);

    conv_silu_kernel<<<NT * DI / 256, 256, 0, stream>>>(xcb, conv_w + i * DI * 4,
                                                        conv_b + i * DI, xinb);

    dim3 g2(1, NT / 64);
    gemm_mfma64<<<g2, 256, 0, stream>>>(xinb, 512, wbl + WB_IN, proj, 48, 48, 0);

    scan_kernel<<<512, 256, 0, stream>>>(xinb, proj, zcb,
                                         dt_w + (size_t)i * DI * 16, dt_b + i * DI,
                                         A_log + (size_t)i * DI * 16, Dp + i * DI, ybf);

    dim3 g3(4, NT / 64);
    gemm_mfma64<<<g3, 256, 0, stream>>>(ybf, 512, wbl + WB_IN + WB_XP, h, 256, 256, 1);
  }

  head_kernel<<<NT, 256, 0, stream>>>(h, fnorm_g, fnorm_b, head_w, head_b, (float*)d_out);
}